// Round 13
// baseline (3763.420 us; speedup 1.0000x reference)
//
#include <hip/hip_runtime.h>
#include <hip/hip_bf16.h>
#include <math.h>

#define Bz   64
#define Sz   512
#define DIN  1024
#define DH   2048
#define DOUT 1024
#define FUT  16
#define KTOT (DIN + DH)   // 3072

typedef __attribute__((ext_vector_type(8))) __bf16 bf16x8;
typedef __attribute__((ext_vector_type(4))) float  f32x4;

union U16x8 { uint4 u; bf16x8 v; };

__device__ __forceinline__ uint4 pack_bf8(float4 a, float4 b) {
  bf16x8 t;
  t[0]=(__bf16)a.x; t[1]=(__bf16)a.y; t[2]=(__bf16)a.z; t[3]=(__bf16)a.w;
  t[4]=(__bf16)b.x; t[5]=(__bf16)b.y; t[6]=(__bf16)b.z; t[7]=(__bf16)b.w;
  U16x8 u; u.v = t; return u.u;
}

// branch-free tanh: 1 - 2/(e^{2x}+1). Saturates to ±1.
__device__ __forceinline__ float fast_tanh(float x) {
  const float e = __builtin_amdgcn_exp2f(2.8853900817779268f * x);
  return 1.0f - 2.0f * __builtin_amdgcn_rcpf(e + 1.0f);
}

// async global->LDS, 16B per lane (dest = wave-uniform base + lane*16)
__device__ __forceinline__ void gload16(const void* g, void* l) {
  __builtin_amdgcn_global_load_lds(
      (const __attribute__((address_space(1))) unsigned int*)g,
      (__attribute__((address_space(3))) unsigned int*)l, 16, 0, 0);
}

#define EPI_SETUP() \
  const int tid = threadIdx.x, lane = tid & 63, wave = tid >> 6; \
  const int wm = (wave >> 1) << 5, wn = (wave & 1) << 5; \
  const int fr = lane & 15, fg = lane >> 4;

// ---------------------------------------------------------------------------
// 64x64-tile GEMM core, BK=128 (half the K-iterations of the old BK=64 core).
// For the latency-bound future-phase kernels. bf16 A and B.
//   LDS[row][c] (c in [0,16)) = global chunk (c ^ (row&15))  [source-swizzled]
//   read of global chunk kq at LDS pos kq ^ (row&15) -> 2-way banks (free).
//   Accumulation order identical to BK=64 core (k ascending).
// ---------------------------------------------------------------------------
__device__ __forceinline__ void gemm128(
    const __bf16* __restrict__ Abase, size_t astride,
    const __bf16* __restrict__ Bbase, size_t bstride,
    int K, f32x4 acc[2][2])
{
  __shared__ uint4 Al[2][1024];   // [buf][row*16 + c], 16KB each
  __shared__ uint4 Bl[2][1024];

  const int tid  = threadIdx.x;
  const int lane = tid & 63;
  const int wave = tid >> 6;
  const int wm = (wave >> 1) << 5;
  const int wn = (wave & 1) << 5;
  const int fr = lane & 15;
  const int fg = lane >> 4;

  const int srow = tid >> 2;        // 64 rows, 4 threads/row
  const int scb  = (tid & 3) << 2;  // 4-chunk base

  const int NK = K >> 7;            // BK = 128

  uint4 ra[4], rb[4];

  auto loadt = [&](int kt) {
    const int kbase = kt << 7;
    #pragma unroll
    for (int i = 0; i < 4; ++i) {
      const int c2 = (scb + i) ^ (srow & 15);   // pre-swizzled source chunk
      ra[i] = *(const uint4*)(Abase + (size_t)srow * astride + kbase + (c2 << 3));
      rb[i] = *(const uint4*)(Bbase + (size_t)srow * bstride + kbase + (c2 << 3));
    }
  };

  auto storet = [&](int buf) {
    #pragma unroll
    for (int i = 0; i < 4; ++i) {
      Al[buf][(srow << 4) + scb + i] = ra[i];
      Bl[buf][(srow << 4) + scb + i] = rb[i];
    }
  };

  loadt(0);
  storet(0);
  __syncthreads();

  for (int kt = 0; kt < NK; ++kt) {
    const int  cur  = kt & 1;
    const bool more = (kt + 1) < NK;
    if (more) loadt(kt + 1);

    #pragma unroll
    for (int kk = 0; kk < 4; ++kk) {
      const int kq = (kk << 2) + fg;
      bf16x8 af[2], bfrag[2];
      #pragma unroll
      for (int mi = 0; mi < 2; ++mi) {
        const int row = wm + mi * 16 + fr;
        U16x8 u; u.u = Al[cur][(row << 4) + (kq ^ (row & 15))]; af[mi] = u.v;
      }
      #pragma unroll
      for (int ni = 0; ni < 2; ++ni) {
        const int row = wn + ni * 16 + fr;
        U16x8 u; u.u = Bl[cur][(row << 4) + (kq ^ (row & 15))]; bfrag[ni] = u.v;
      }
      #pragma unroll
      for (int mi = 0; mi < 2; ++mi)
        #pragma unroll
        for (int ni = 0; ni < 2; ++ni)
          acc[mi][ni] = __builtin_amdgcn_mfma_f32_16x16x32_bf16(
              af[mi], bfrag[ni], acc[mi][ni], 0, 0, 0);
    }

    __syncthreads();
    if (more) storet((kt + 1) & 1);
    __syncthreads();
  }
}

// ---------------------------------------------------------------------------
__global__ __launch_bounds__(256) void k_transp(const float* __restrict__ W,
                                                __bf16* __restrict__ WT,
                                                int K, int N)
{
  __shared__ float T[64][65];
  const int k0 = blockIdx.x << 6, n0 = blockIdx.y << 6;
  const int c = threadIdx.x & 63, r4 = threadIdx.x >> 6;
  #pragma unroll
  for (int rr = 0; rr < 16; ++rr) {
    const int r = rr * 4 + r4;
    T[r][c] = W[(size_t)(k0 + r) * N + n0 + c];
  }
  __syncthreads();
  #pragma unroll
  for (int rr = 0; rr < 16; ++rr) {
    const int r = rr * 4 + r4;
    WT[(size_t)(n0 + r) * K + k0 + c] = (__bf16)T[c][r];
  }
}

// ---------------------------------------------------------------------------
// Phase A (m97-style 128x128): HX[s][b][n] = bf16(x_row . Wx[:,n] + bh[n])
// ---------------------------------------------------------------------------
__global__ __launch_bounds__(256) void k_xw128(const float* __restrict__ x,
                                               const __bf16* __restrict__ WhT,
                                               const float* __restrict__ bh,
                                               __bf16* __restrict__ HX)
{
  __shared__ __align__(16) uint4 As[1024];   // [128 rows][8 chunks] bf16
  __shared__ __align__(16) uint4 Bs[1024];

  const int n0 = blockIdx.x << 7;
  const int m0 = blockIdx.y << 7;
  const int tid = threadIdx.x, lane = tid & 63, w = tid >> 6;
  const int wr = w >> 1, wc = w & 1;
  const int fr = lane & 15, fg = lane >> 4;

  const int sr  = tid >> 3;            // staging row (of 128, +32j)
  const int sq  = tid & 7;             // LDS chunk col
  const int sq2 = sq ^ (sr & 7);       // swizzled source chunk col

  f32x4 acc[4][4] = {};

  for (int kt = 0; kt < DIN / 64; ++kt) {
    const int ko = kt << 6;
    #pragma unroll
    for (int j = 0; j < 4; ++j) {
      const float* ap = x + (size_t)(m0 + sr + 32 * j) * DIN + ko + (sq2 << 3);
      float4 a0 = *(const float4*)ap;
      float4 a1 = *(const float4*)(ap + 4);
      As[((sr + 32 * j) << 3) + sq] = pack_bf8(a0, a1);
      gload16(WhT + (size_t)(n0 + sr + 32 * j) * KTOT + ko + (sq2 << 3),
              (char*)Bs + (tid << 4) + (j << 12));
    }
    __syncthreads();
    #pragma unroll
    for (int kk = 0; kk < 2; ++kk) {
      bf16x8 af[4], bf_[4];
      const int kq = (kk << 2) + fg;
      #pragma unroll
      for (int mi = 0; mi < 4; ++mi) {
        const int row = (wr << 6) + (mi << 4) + fr;
        U16x8 u; u.u = As[(row << 3) + (kq ^ (row & 7))]; af[mi] = u.v;
      }
      #pragma unroll
      for (int ni = 0; ni < 4; ++ni) {
        const int row = (wc << 6) + (ni << 4) + fr;
        U16x8 u; u.u = Bs[(row << 3) + (kq ^ (row & 7))]; bf_[ni] = u.v;
      }
      #pragma unroll
      for (int mi = 0; mi < 4; ++mi)
        #pragma unroll
        for (int ni = 0; ni < 4; ++ni)
          acc[mi][ni] = __builtin_amdgcn_mfma_f32_16x16x32_bf16(
              af[mi], bf_[ni], acc[mi][ni], 0, 0, 0);
    }
    __syncthreads();
  }

  #pragma unroll
  for (int ni = 0; ni < 4; ++ni) {
    const int n = n0 + (wc << 6) + (ni << 4) + fr;
    const float bn = bh[n];
    #pragma unroll
    for (int mi = 0; mi < 4; ++mi)
      #pragma unroll
      for (int rr = 0; rr < 4; ++rr) {
        const int gf = m0 + (wr << 6) + (mi << 4) + (fg << 2) + rr;
        const int b = gf >> 9, s = gf & 511;     // row = b*512+s
        HX[((size_t)s * Bz + b) * DH + n] = (__bf16)(acc[mi][ni][rr] + bn);
      }
  }
}

// ---------------------------------------------------------------------------
// Phase C (m97-style 128x128): out[b][s][n] = HX_row . Wo[:,n] + bo[n]
// ---------------------------------------------------------------------------
__global__ __launch_bounds__(256) void k_out128(const __bf16* __restrict__ HX,
                                                const __bf16* __restrict__ WoT,
                                                const float* __restrict__ bo,
                                                float* __restrict__ out)
{
  __shared__ __align__(16) uint4 As[1024];
  __shared__ __align__(16) uint4 Bs[1024];

  const int n0 = blockIdx.x << 7;
  const int m0 = blockIdx.y << 7;
  const int tid = threadIdx.x, lane = tid & 63, w = tid >> 6;
  const int wr = w >> 1, wc = w & 1;
  const int fr = lane & 15, fg = lane >> 4;

  const int sr  = tid >> 3;
  const int sq  = tid & 7;
  const int sq2 = sq ^ (sr & 7);

  f32x4 acc[4][4] = {};

  for (int kt = 0; kt < DH / 64; ++kt) {
    const int ko = kt << 6;
    #pragma unroll
    for (int j = 0; j < 4; ++j) {
      gload16(HX + (size_t)(m0 + sr + 32 * j) * DH + ko + (sq2 << 3),
              (char*)As + (tid << 4) + (j << 12));
      gload16(WoT + (size_t)(n0 + sr + 32 * j) * DH + ko + (sq2 << 3),
              (char*)Bs + (tid << 4) + (j << 12));
    }
    __syncthreads();
    #pragma unroll
    for (int kk = 0; kk < 2; ++kk) {
      bf16x8 af[4], bf_[4];
      const int kq = (kk << 2) + fg;
      #pragma unroll
      for (int mi = 0; mi < 4; ++mi) {
        const int row = (wr << 6) + (mi << 4) + fr;
        U16x8 u; u.u = As[(row << 3) + (kq ^ (row & 7))]; af[mi] = u.v;
      }
      #pragma unroll
      for (int ni = 0; ni < 4; ++ni) {
        const int row = (wc << 6) + (ni << 4) + fr;
        U16x8 u; u.u = Bs[(row << 3) + (kq ^ (row & 7))]; bf_[ni] = u.v;
      }
      #pragma unroll
      for (int mi = 0; mi < 4; ++mi)
        #pragma unroll
        for (int ni = 0; ni < 4; ++ni)
          acc[mi][ni] = __builtin_amdgcn_mfma_f32_16x16x32_bf16(
              af[mi], bf_[ni], acc[mi][ni], 0, 0, 0);
    }
    __syncthreads();
  }

  #pragma unroll
  for (int ni = 0; ni < 4; ++ni) {
    const int n = n0 + (wc << 6) + (ni << 4) + fr;
    const float bn = bo[n];
    #pragma unroll
    for (int mi = 0; mi < 4; ++mi)
      #pragma unroll
      for (int rr = 0; rr < 4; ++rr) {
        const int gf = m0 + (wr << 6) + (mi << 4) + (fg << 2) + rr;
        const int s = gf >> 6, b = gf & 63;      // row = s*64+b
        out[((size_t)b * Sz + s) * DOUT + n] = acc[mi][ni][rr] + bn;
      }
  }
}

// ---------------------------------------------------------------------------
// Persistent RNN recurrence — r8's PROVEN protocol (sc0sc1 LLC flags).
// UNCHANGED from r11.
// ---------------------------------------------------------------------------
__global__ __launch_bounds__(512, 2) void k_rnn(const __bf16* __restrict__ WhT,
                                                __bf16* __restrict__ HX,
                                                unsigned int* __restrict__ flags)
{
  __shared__ __align__(16) float RED[8 * 1056];   // 8 planes x [16][66]

  const int mb    = blockIdx.x & 3;
  const int nb    = blockIdx.x >> 2;      // 0..31
  const int nbase = nb << 6;              // 64-col slice
  const int tid   = threadIdx.x;
  const int lane  = tid & 63;
  const int w     = tid >> 6;             // 0..7 (K-eighth owner)
  const int l15   = lane & 15;
  const int l4    = lane >> 4;
  const int wavek = w << 8;               // K range [wavek, wavek+256)

  // ---- Whh slice resident as B-fragments ----
  bf16x8 wf[8][4];
  {
    const __bf16* wb = WhT + (size_t)(nbase + l15) * KTOT + DIN + wavek + (l4 << 3);
    #pragma unroll
    for (int kk = 0; kk < 8; ++kk)
      #pragma unroll
      for (int nt = 0; nt < 4; ++nt)
        wf[kk][nt] = *(const bf16x8*)(wb + (size_t)nt * 16 * KTOT + kk * 32);
  }

  // output mapping (reduce phase): 512 threads = 16 rows x 32 col-pairs
  const int orow = tid >> 5;
  const int cp   = tid & 31;
  const int grow = (mb << 4) + orow;
  const int gcol = nbase + (cp << 1);

  for (int t = 0; t < Sz; ++t) {
    __bf16* Hc = HX + (size_t)t * Bz * DH;

    // XW prefetch via sc0sc1 (no L2 fill of soon-to-be-overwritten lines)
    unsigned int xwp;
    asm volatile("global_load_dword %0, %1, off sc0 sc1"
                 : "=v"(xwp)
                 : "v"((const void*)(Hc + (size_t)grow * DH + gcol))
                 : "memory");

    f32x4 acc[4] = {};

    if (t > 0) {
      // poll this wave's 4 producers
      const unsigned int* fl = flags
          + (((size_t)(t - 1) * 4 + mb) << 7) + (((w << 2) + (lane & 3)) << 2);
      for (;;) {
        unsigned int f;
        asm volatile("global_load_dword %0, %1, off sc0 sc1\n\t"
                     "s_waitcnt vmcnt(0)"
                     : "=v"(f) : "v"((const void*)fl) : "memory");
        if (__all((int)(f == 1u))) break;
        __builtin_amdgcn_s_sleep(1);
      }

      // cached A-loads (L2-dedup within XCD)
      const __bf16* Hp = HX + (size_t)(t - 1) * Bz * DH
                       + (size_t)((mb << 4) + l15) * DH + wavek + (l4 << 3);
      bf16x8 a[8];
      #pragma unroll
      for (int kk = 0; kk < 8; ++kk)
        a[kk] = *(const bf16x8*)(Hp + kk * 32);

      #pragma unroll
      for (int kk = 0; kk < 8; ++kk)
        #pragma unroll
        for (int nt = 0; nt < 4; ++nt)
          asm("v_mfma_f32_16x16x32_bf16 %0, %1, %2, %0"
              : "+v"(acc[nt]) : "v"(a[kk]), "a"(wf[kk][nt]));
    }

    // ---- 8-wave K reduction through padded LDS ----
    #pragma unroll
    for (int nt = 0; nt < 4; ++nt)
      #pragma unroll
      for (int r = 0; r < 4; ++r)
        RED[w * 1056 + ((l4 << 2) + r) * 66 + (nt << 4) + l15] = acc[nt][r];
    __syncthreads();

    float sx = 0.f, sy = 0.f;
    #pragma unroll
    for (int p = 0; p < 8; ++p) {
      const float2 v = *(const float2*)&RED[p * 1056 + orow * 66 + (cp << 1)];
      sx += v.x; sy += v.y;
    }

    asm volatile("s_waitcnt vmcnt(0)" : "+v"(xwp) :: "memory");
    union { unsigned int u; __bf16 h[2]; } ux; ux.u = xwp;
    union { unsigned int u; __bf16 h[2]; } po;
    po.h[0] = (__bf16)fast_tanh(sx + (float)ux.h[0]);
    po.h[1] = (__bf16)fast_tanh(sy + (float)ux.h[1]);

    asm volatile("global_store_dword %0, %1, off sc0 sc1"
                 :: "v"((void*)(Hc + (size_t)grow * DH + gcol)), "v"(po.u)
                 : "memory");
    asm volatile("s_waitcnt vmcnt(0)" ::: "memory");   // acked at LLC
    __syncthreads();
    if (tid == 0) {
      unsigned int* fp = flags + (((size_t)t * 4 + mb) << 7) + (nb << 2);
      asm volatile("global_store_dword %0, %1, off sc0 sc1"
                   :: "v"((void*)fp), "v"(1u) : "memory");
    }
  }
}

// ---------------------------------------------------------------------------
__global__ __launch_bounds__(256) void k_finit(const float* __restrict__ x,
                                               const __bf16* __restrict__ HX,
                                               __bf16* __restrict__ zf0)
{
  const int b = blockIdx.x;
  for (int k = threadIdx.x; k < DIN; k += 256)
    zf0[(size_t)b * KTOT + k] =
        (__bf16)x[((size_t)b * Sz + (Sz - 1)) * DIN + k];
  for (int k = threadIdx.x; k < DH; k += 256)
    zf0[(size_t)b * KTOT + DIN + k] =
        HX[(size_t)(Sz - 1) * Bz * DH + (size_t)b * DH + k];
}

// ---------------------------------------------------------------------------
// Future h-step (BK=128 core): zn.h = bf16(tanh( zc . Wh + bh )), K=3072
// ---------------------------------------------------------------------------
__global__ __launch_bounds__(256) void k_fstep2(const __bf16* __restrict__ zc,
                                                __bf16* __restrict__ zn,
                                                const __bf16* __restrict__ WhT,
                                                const float* __restrict__ bh)
{
  const int n0 = blockIdx.x << 6;
  f32x4 acc[2][2] = {};
  gemm128(zc, KTOT, WhT + (size_t)n0 * KTOT, KTOT, KTOT, acc);
  EPI_SETUP();
  #pragma unroll
  for (int mi = 0; mi < 2; ++mi)
    #pragma unroll
    for (int ni = 0; ni < 2; ++ni)
      #pragma unroll
      for (int r = 0; r < 4; ++r) {
        const int m = wm + mi * 16 + fg * 4 + r;
        const int n = n0 + wn + ni * 16 + fr;
        zn[(size_t)m * KTOT + DIN + n] = (__bf16)fast_tanh(acc[mi][ni][r] + bh[n]);
      }
}

// ---------------------------------------------------------------------------
// Future out-step (BK=128 core): pred = zn.h . Wo + bo ; zn.inp = bf16(pred)
// ---------------------------------------------------------------------------
__global__ __launch_bounds__(256) void k_fout2(__bf16* __restrict__ zn,
                                               const __bf16* __restrict__ WoT,
                                               const float* __restrict__ bo,
                                               float* __restrict__ pred,
                                               int f)
{
  const int n0 = blockIdx.x << 6;
  f32x4 acc[2][2] = {};
  gemm128(zn + DIN, KTOT, WoT + (size_t)n0 * DH, DH, DH, acc);
  EPI_SETUP();
  #pragma unroll
  for (int mi = 0; mi < 2; ++mi)
    #pragma unroll
    for (int ni = 0; ni < 2; ++ni)
      #pragma unroll
      for (int r = 0; r < 4; ++r) {
        const int m = wm + mi * 16 + fg * 4 + r;
        const int n = n0 + wn + ni * 16 + fr;
        const float v = acc[mi][ni][r] + bo[n];
        pred[((size_t)m * FUT + f) * DOUT + n] = v;
        zn[(size_t)m * KTOT + n] = (__bf16)v;
      }
}

// ---------------------------------------------------------------------------
extern "C" void kernel_launch(void* const* d_in, const int* in_sizes, int n_in,
                              void* d_out, int out_size, void* d_ws, size_t ws_size,
                              hipStream_t stream)
{
  const float* x  = (const float*)d_in[0];
  const float* Wh = (const float*)d_in[1];
  const float* bh = (const float*)d_in[2];
  const float* Wo = (const float*)d_in[3];
  const float* bo = (const float*)d_in[4];

  char* ws = (char*)d_ws;
  __bf16* WhT = (__bf16*)ws;                               // [DH][KTOT]   12 MB
  __bf16* WoT = WhT + (size_t)DH * KTOT;                   // [DOUT][DH]    4 MB
  __bf16* HX  = WoT + (size_t)DOUT * DH;                   // [Sz][Bz][DH] 128 MB
  __bf16* zf  = HX + (size_t)Sz * Bz * DH;                 // [2][Bz][KTOT] .8 MB
  unsigned int* flags = (unsigned int*)(zf + (size_t)2 * Bz * KTOT); // 1 MB

  float* out  = (float*)d_out;
  float* pred = out + (size_t)Bz * Sz * DOUT;

  const dim3 blk(256);

  k_transp<<<dim3(KTOT / 64, DH / 64), blk, 0, stream>>>(Wh, WhT, KTOT, DH);
  k_transp<<<dim3(DH / 64, DOUT / 64), blk, 0, stream>>>(Wo, WoT, DH, DOUT);

  hipMemsetAsync(flags, 0, (size_t)Sz * 4 * 128 * sizeof(unsigned int), stream);

  k_xw128<<<dim3(DH / 128, (Bz * Sz) / 128), blk, 0, stream>>>(x, WhT, bh, HX);

  {
    const __bf16* a0 = WhT; __bf16* a1 = HX; unsigned int* a2 = flags;
    void* args[] = { (void*)&a0, (void*)&a1, (void*)&a2 };
    hipLaunchCooperativeKernel((const void*)k_rnn, dim3(128), dim3(512), args,
                               0, stream);
  }

  k_out128<<<dim3(DOUT / 128, (Bz * Sz) / 128), blk, 0, stream>>>(HX, WoT, bo, out);

  k_finit<<<dim3(Bz), blk, 0, stream>>>(x, HX, zf);
  for (int f = 0; f < FUT; ++f) {
    __bf16* zc = zf + (size_t)(f & 1) * Bz * KTOT;
    __bf16* zn = zf + (size_t)((f & 1) ^ 1) * Bz * KTOT;
    k_fstep2<<<dim3(DH / 64), blk, 0, stream>>>(zc, zn, WhT, bh);
    k_fout2<<<dim3(DOUT / 64), blk, 0, stream>>>(zn, WoT, bo, pred, f);
  }
}

// Round 14
// 3223.196 us; speedup vs baseline: 1.1676x; 1.1676x over previous
//
#include <hip/hip_runtime.h>
#include <hip/hip_bf16.h>
#include <math.h>

#define Bz   64
#define Sz   512
#define DIN  1024
#define DH   2048
#define DOUT 1024
#define FUT  16
#define KTOT (DIN + DH)   // 3072

typedef __attribute__((ext_vector_type(8))) __bf16 bf16x8;
typedef __attribute__((ext_vector_type(4))) float  f32x4;

union U16x8 { uint4 u; bf16x8 v; };

__device__ __forceinline__ uint4 pack_bf8(float4 a, float4 b) {
  bf16x8 t;
  t[0]=(__bf16)a.x; t[1]=(__bf16)a.y; t[2]=(__bf16)a.z; t[3]=(__bf16)a.w;
  t[4]=(__bf16)b.x; t[5]=(__bf16)b.y; t[6]=(__bf16)b.z; t[7]=(__bf16)b.w;
  U16x8 u; u.v = t; return u.u;
}

// branch-free tanh: 1 - 2/(e^{2x}+1). Saturates to ±1.
__device__ __forceinline__ float fast_tanh(float x) {
  const float e = __builtin_amdgcn_exp2f(2.8853900817779268f * x);
  return 1.0f - 2.0f * __builtin_amdgcn_rcpf(e + 1.0f);
}

// async global->LDS, 16B per lane (dest = wave-uniform base + lane*16)
__device__ __forceinline__ void gload16(const void* g, void* l) {
  __builtin_amdgcn_global_load_lds(
      (const __attribute__((address_space(1))) unsigned int*)g,
      (__attribute__((address_space(3))) unsigned int*)l, 16, 0, 0);
}

// ---------------------------------------------------------------------------
// 64x64-tile GEMM core (future-phase kernels)
// ---------------------------------------------------------------------------
template<bool AF32>
__device__ __forceinline__ void gemm_core(
    const void* __restrict__ Abase, size_t astride,
    const __bf16* __restrict__ Bbase, size_t bstride,
    int K, f32x4 acc[2][2])
{
  __shared__ uint4 Al[2][512];
  __shared__ uint4 Bl[2][512];

  const int tid  = threadIdx.x;
  const int lane = tid & 63;
  const int wave = tid >> 6;
  const int wm = (wave >> 1) << 5;
  const int wn = (wave & 1) << 5;
  const int fr = lane & 15;
  const int fg = lane >> 4;

  const int srow = tid >> 2;
  const int sck  = (tid & 3) << 1;

  const int NK = K >> 6;
  if (NK <= 0) return;

  uint4 ra0, ra1, rb0, rb1;

  auto loadt = [&](int kt) {
    const int kelt = (kt << 6) + (sck << 3);
    if constexpr (AF32) {
      const float* ap = (const float*)Abase + (size_t)srow * astride + kelt;
      float4 a0 = *(const float4*)(ap);
      float4 a1 = *(const float4*)(ap + 4);
      float4 a2 = *(const float4*)(ap + 8);
      float4 a3 = *(const float4*)(ap + 12);
      ra0 = pack_bf8(a0, a1);
      ra1 = pack_bf8(a2, a3);
    } else {
      const __bf16* ap = (const __bf16*)Abase + (size_t)srow * astride + kelt;
      ra0 = *(const uint4*)(ap);
      ra1 = *(const uint4*)(ap + 8);
    }
    const __bf16* bp = Bbase + (size_t)srow * bstride + kelt;
    rb0 = *(const uint4*)(bp);
    rb1 = *(const uint4*)(bp + 8);
  };

  auto storet = [&](int buf) {
    const int x7 = srow & 7;
    Al[buf][srow * 8 + ( sck      ^ x7)] = ra0;
    Al[buf][srow * 8 + ((sck + 1) ^ x7)] = ra1;
    Bl[buf][srow * 8 + ( sck      ^ x7)] = rb0;
    Bl[buf][srow * 8 + ((sck + 1) ^ x7)] = rb1;
  };

  loadt(0);
  storet(0);
  __syncthreads();

  for (int kt = 0; kt < NK; ++kt) {
    const int  cur  = kt & 1;
    const bool more = (kt + 1) < NK;
    if (more) loadt(kt + 1);

    #pragma unroll
    for (int kk = 0; kk < 2; ++kk) {
      bf16x8 af[2], bfrag[2];
      #pragma unroll
      for (int mi = 0; mi < 2; ++mi) {
        const int row = wm + mi * 16 + fr;
        const int ck  = (kk * 4 + fg) ^ (row & 7);
        U16x8 u; u.u = Al[cur][row * 8 + ck]; af[mi] = u.v;
      }
      #pragma unroll
      for (int ni = 0; ni < 2; ++ni) {
        const int row = wn + ni * 16 + fr;
        const int ck  = (kk * 4 + fg) ^ (row & 7);
        U16x8 u; u.u = Bl[cur][row * 8 + ck]; bfrag[ni] = u.v;
      }
      #pragma unroll
      for (int mi = 0; mi < 2; ++mi)
        #pragma unroll
        for (int ni = 0; ni < 2; ++ni)
          acc[mi][ni] = __builtin_amdgcn_mfma_f32_16x16x32_bf16(
              af[mi], bfrag[ni], acc[mi][ni], 0, 0, 0);
    }

    __syncthreads();
    if (more) storet((kt + 1) & 1);
    __syncthreads();
  }
}

#define EPI_SETUP() \
  const int tid = threadIdx.x, lane = tid & 63, wave = tid >> 6; \
  const int wm = (wave >> 1) << 5, wn = (wave & 1) << 5; \
  const int fr = lane & 15, fg = lane >> 4;

// ---------------------------------------------------------------------------
__global__ __launch_bounds__(256) void k_transp(const float* __restrict__ W,
                                                __bf16* __restrict__ WT,
                                                int K, int N)
{
  __shared__ float T[64][65];
  const int k0 = blockIdx.x << 6, n0 = blockIdx.y << 6;
  const int c = threadIdx.x & 63, r4 = threadIdx.x >> 6;
  #pragma unroll
  for (int rr = 0; rr < 16; ++rr) {
    const int r = rr * 4 + r4;
    T[r][c] = W[(size_t)(k0 + r) * N + n0 + c];
  }
  __syncthreads();
  #pragma unroll
  for (int rr = 0; rr < 16; ++rr) {
    const int r = rr * 4 + r4;
    WT[(size_t)(n0 + r) * K + k0 + c] = (__bf16)T[c][r];
  }
}

// ---------------------------------------------------------------------------
// Phase A (m97-style 128x128): HX[s][b][n] = bf16(x_row . Wx[:,n] + bh[n])
// ---------------------------------------------------------------------------
__global__ __launch_bounds__(256) void k_xw128(const float* __restrict__ x,
                                               const __bf16* __restrict__ WhT,
                                               const float* __restrict__ bh,
                                               __bf16* __restrict__ HX)
{
  __shared__ __align__(16) uint4 As[1024];   // [128 rows][8 chunks] bf16
  __shared__ __align__(16) uint4 Bs[1024];

  const int n0 = blockIdx.x << 7;
  const int m0 = blockIdx.y << 7;
  const int tid = threadIdx.x, lane = tid & 63, w = tid >> 6;
  const int wr = w >> 1, wc = w & 1;
  const int fr = lane & 15, fg = lane >> 4;

  const int sr  = tid >> 3;            // staging row (of 128, +32j)
  const int sq  = tid & 7;             // LDS chunk col
  const int sq2 = sq ^ (sr & 7);       // swizzled source chunk col

  f32x4 acc[4][4] = {};

  for (int kt = 0; kt < DIN / 64; ++kt) {
    const int ko = kt << 6;
    #pragma unroll
    for (int j = 0; j < 4; ++j) {
      const float* ap = x + (size_t)(m0 + sr + 32 * j) * DIN + ko + (sq2 << 3);
      float4 a0 = *(const float4*)ap;
      float4 a1 = *(const float4*)(ap + 4);
      As[((sr + 32 * j) << 3) + sq] = pack_bf8(a0, a1);
      gload16(WhT + (size_t)(n0 + sr + 32 * j) * KTOT + ko + (sq2 << 3),
              (char*)Bs + (tid << 4) + (j << 12));
    }
    __syncthreads();
    #pragma unroll
    for (int kk = 0; kk < 2; ++kk) {
      bf16x8 af[4], bf_[4];
      const int kq = (kk << 2) + fg;
      #pragma unroll
      for (int mi = 0; mi < 4; ++mi) {
        const int row = (wr << 6) + (mi << 4) + fr;
        U16x8 u; u.u = As[(row << 3) + (kq ^ (row & 7))]; af[mi] = u.v;
      }
      #pragma unroll
      for (int ni = 0; ni < 4; ++ni) {
        const int row = (wc << 6) + (ni << 4) + fr;
        U16x8 u; u.u = Bs[(row << 3) + (kq ^ (row & 7))]; bf_[ni] = u.v;
      }
      #pragma unroll
      for (int mi = 0; mi < 4; ++mi)
        #pragma unroll
        for (int ni = 0; ni < 4; ++ni)
          acc[mi][ni] = __builtin_amdgcn_mfma_f32_16x16x32_bf16(
              af[mi], bf_[ni], acc[mi][ni], 0, 0, 0);
    }
    __syncthreads();
  }

  #pragma unroll
  for (int ni = 0; ni < 4; ++ni) {
    const int n = n0 + (wc << 6) + (ni << 4) + fr;
    const float bn = bh[n];
    #pragma unroll
    for (int mi = 0; mi < 4; ++mi)
      #pragma unroll
      for (int rr = 0; rr < 4; ++rr) {
        const int gf = m0 + (wr << 6) + (mi << 4) + (fg << 2) + rr;
        const int b = gf >> 9, s = gf & 511;     // row = b*512+s
        HX[((size_t)s * Bz + b) * DH + n] = (__bf16)(acc[mi][ni][rr] + bn);
      }
  }
}

// ---------------------------------------------------------------------------
// Phase C (m97-style 128x128): out[b][s][n] = HX_row . Wo[:,n] + bo[n]
// ---------------------------------------------------------------------------
__global__ __launch_bounds__(256) void k_out128(const __bf16* __restrict__ HX,
                                                const __bf16* __restrict__ WoT,
                                                const float* __restrict__ bo,
                                                float* __restrict__ out)
{
  __shared__ __align__(16) uint4 As[1024];
  __shared__ __align__(16) uint4 Bs[1024];

  const int n0 = blockIdx.x << 7;
  const int m0 = blockIdx.y << 7;
  const int tid = threadIdx.x, lane = tid & 63, w = tid >> 6;
  const int wr = w >> 1, wc = w & 1;
  const int fr = lane & 15, fg = lane >> 4;

  const int sr  = tid >> 3;
  const int sq  = tid & 7;
  const int sq2 = sq ^ (sr & 7);

  f32x4 acc[4][4] = {};

  for (int kt = 0; kt < DH / 64; ++kt) {
    const int ko = kt << 6;
    #pragma unroll
    for (int j = 0; j < 4; ++j) {
      gload16(HX + (size_t)(m0 + sr + 32 * j) * DH + ko + (sq2 << 3),
              (char*)As + (tid << 4) + (j << 12));
      gload16(WoT + (size_t)(n0 + sr + 32 * j) * DH + ko + (sq2 << 3),
              (char*)Bs + (tid << 4) + (j << 12));
    }
    __syncthreads();
    #pragma unroll
    for (int kk = 0; kk < 2; ++kk) {
      bf16x8 af[4], bf_[4];
      const int kq = (kk << 2) + fg;
      #pragma unroll
      for (int mi = 0; mi < 4; ++mi) {
        const int row = (wr << 6) + (mi << 4) + fr;
        U16x8 u; u.u = As[(row << 3) + (kq ^ (row & 7))]; af[mi] = u.v;
      }
      #pragma unroll
      for (int ni = 0; ni < 4; ++ni) {
        const int row = (wc << 6) + (ni << 4) + fr;
        U16x8 u; u.u = Bs[(row << 3) + (kq ^ (row & 7))]; bf_[ni] = u.v;
      }
      #pragma unroll
      for (int mi = 0; mi < 4; ++mi)
        #pragma unroll
        for (int ni = 0; ni < 4; ++ni)
          acc[mi][ni] = __builtin_amdgcn_mfma_f32_16x16x32_bf16(
              af[mi], bf_[ni], acc[mi][ni], 0, 0, 0);
    }
    __syncthreads();
  }

  #pragma unroll
  for (int ni = 0; ni < 4; ++ni) {
    const int n = n0 + (wc << 6) + (ni << 4) + fr;
    const float bn = bo[n];
    #pragma unroll
    for (int mi = 0; mi < 4; ++mi)
      #pragma unroll
      for (int rr = 0; rr < 4; ++rr) {
        const int gf = m0 + (wr << 6) + (mi << 4) + (fg << 2) + rr;
        const int s = gf >> 6, b = gf & 63;      // row = s*64+b
        out[((size_t)b * Sz + s) * DOUT + n] = acc[mi][ni][rr] + bn;
      }
  }
}

// ---------------------------------------------------------------------------
// Persistent RNN recurrence — r8's PROVEN protocol (sc0sc1 LLC flags):
//   sc0sc1 XW prefetch, per-wave 4-producer flag poll, cached A-loads,
//   sc0sc1 h store + vmcnt ack + barrier + tid0 flag publish.
// ---------------------------------------------------------------------------
__global__ __launch_bounds__(512, 2) void k_rnn(const __bf16* __restrict__ WhT,
                                                __bf16* __restrict__ HX,
                                                unsigned int* __restrict__ flags)
{
  __shared__ __align__(16) float RED[8 * 1056];   // 8 planes x [16][66]

  const int mb    = blockIdx.x & 3;
  const int nb    = blockIdx.x >> 2;      // 0..31
  const int nbase = nb << 6;              // 64-col slice
  const int tid   = threadIdx.x;
  const int lane  = tid & 63;
  const int w     = tid >> 6;             // 0..7 (K-eighth owner)
  const int l15   = lane & 15;
  const int l4    = lane >> 4;
  const int wavek = w << 8;               // K range [wavek, wavek+256)

  // ---- Whh slice resident as B-fragments ----
  bf16x8 wf[8][4];
  {
    const __bf16* wb = WhT + (size_t)(nbase + l15) * KTOT + DIN + wavek + (l4 << 3);
    #pragma unroll
    for (int kk = 0; kk < 8; ++kk)
      #pragma unroll
      for (int nt = 0; nt < 4; ++nt)
        wf[kk][nt] = *(const bf16x8*)(wb + (size_t)nt * 16 * KTOT + kk * 32);
  }

  // output mapping (reduce phase): 512 threads = 16 rows x 32 col-pairs
  const int orow = tid >> 5;
  const int cp   = tid & 31;
  const int grow = (mb << 4) + orow;
  const int gcol = nbase + (cp << 1);

  for (int t = 0; t < Sz; ++t) {
    __bf16* Hc = HX + (size_t)t * Bz * DH;

    // XW prefetch via sc0sc1 (no L2 fill of soon-to-be-overwritten lines)
    unsigned int xwp;
    asm volatile("global_load_dword %0, %1, off sc0 sc1"
                 : "=v"(xwp)
                 : "v"((const void*)(Hc + (size_t)grow * DH + gcol))
                 : "memory");

    f32x4 acc[4] = {};

    if (t > 0) {
      // poll this wave's 4 producers
      const unsigned int* fl = flags
          + (((size_t)(t - 1) * 4 + mb) << 7) + (((w << 2) + (lane & 3)) << 2);
      for (;;) {
        unsigned int f;
        asm volatile("global_load_dword %0, %1, off sc0 sc1\n\t"
                     "s_waitcnt vmcnt(0)"
                     : "=v"(f) : "v"((const void*)fl) : "memory");
        if (__all((int)(f == 1u))) break;
        __builtin_amdgcn_s_sleep(1);
      }

      // cached A-loads (L2-dedup within XCD)
      const __bf16* Hp = HX + (size_t)(t - 1) * Bz * DH
                       + (size_t)((mb << 4) + l15) * DH + wavek + (l4 << 3);
      bf16x8 a[8];
      #pragma unroll
      for (int kk = 0; kk < 8; ++kk)
        a[kk] = *(const bf16x8*)(Hp + kk * 32);

      #pragma unroll
      for (int kk = 0; kk < 8; ++kk)
        #pragma unroll
        for (int nt = 0; nt < 4; ++nt)
          asm("v_mfma_f32_16x16x32_bf16 %0, %1, %2, %0"
              : "+v"(acc[nt]) : "v"(a[kk]), "a"(wf[kk][nt]));
    }

    // ---- 8-wave K reduction through padded LDS ----
    #pragma unroll
    for (int nt = 0; nt < 4; ++nt)
      #pragma unroll
      for (int r = 0; r < 4; ++r)
        RED[w * 1056 + ((l4 << 2) + r) * 66 + (nt << 4) + l15] = acc[nt][r];
    __syncthreads();

    float sx = 0.f, sy = 0.f;
    #pragma unroll
    for (int p = 0; p < 8; ++p) {
      const float2 v = *(const float2*)&RED[p * 1056 + orow * 66 + (cp << 1)];
      sx += v.x; sy += v.y;
    }

    asm volatile("s_waitcnt vmcnt(0)" : "+v"(xwp) :: "memory");
    union { unsigned int u; __bf16 h[2]; } ux; ux.u = xwp;
    union { unsigned int u; __bf16 h[2]; } po;
    po.h[0] = (__bf16)fast_tanh(sx + (float)ux.h[0]);
    po.h[1] = (__bf16)fast_tanh(sy + (float)ux.h[1]);

    asm volatile("global_store_dword %0, %1, off sc0 sc1"
                 :: "v"((void*)(Hc + (size_t)grow * DH + gcol)), "v"(po.u)
                 : "memory");
    asm volatile("s_waitcnt vmcnt(0)" ::: "memory");   // acked at LLC
    __syncthreads();
    if (tid == 0) {
      unsigned int* fp = flags + (((size_t)t * 4 + mb) << 7) + (nb << 2);
      asm volatile("global_store_dword %0, %1, off sc0 sc1"
                   :: "v"((void*)fp), "v"(1u) : "memory");
    }
  }
}

// ---------------------------------------------------------------------------
__global__ __launch_bounds__(256) void k_finit(const float* __restrict__ x,
                                               const __bf16* __restrict__ HX,
                                               __bf16* __restrict__ zf0)
{
  const int b = blockIdx.x;
  for (int k = threadIdx.x; k < DIN; k += 256)
    zf0[(size_t)b * KTOT + k] =
        (__bf16)x[((size_t)b * Sz + (Sz - 1)) * DIN + k];
  for (int k = threadIdx.x; k < DH; k += 256)
    zf0[(size_t)b * KTOT + DIN + k] =
        HX[(size_t)(Sz - 1) * Bz * DH + (size_t)b * DH + k];
}

__global__ __launch_bounds__(256) void k_fstep(const __bf16* __restrict__ zc,
                                               __bf16* __restrict__ zn,
                                               const __bf16* __restrict__ WhT,
                                               const float* __restrict__ bh)
{
  const int n0 = blockIdx.x << 6;
  f32x4 acc[2][2] = {};
  gemm_core<false>(zc, KTOT, WhT + (size_t)n0 * KTOT, KTOT, KTOT, acc);
  EPI_SETUP();
  #pragma unroll
  for (int mi = 0; mi < 2; ++mi)
    #pragma unroll
    for (int ni = 0; ni < 2; ++ni)
      #pragma unroll
      for (int r = 0; r < 4; ++r) {
        const int m = wm + mi * 16 + fg * 4 + r;
        const int n = n0 + wn + ni * 16 + fr;
        zn[(size_t)m * KTOT + DIN + n] = (__bf16)fast_tanh(acc[mi][ni][r] + bh[n]);
      }
}

__global__ __launch_bounds__(256) void k_fout(__bf16* __restrict__ zn,
                                              const __bf16* __restrict__ WoT,
                                              const float* __restrict__ bo,
                                              float* __restrict__ pred,
                                              int f)
{
  const int n0 = blockIdx.x << 6;
  f32x4 acc[2][2] = {};
  gemm_core<false>(zn + DIN, KTOT, WoT + (size_t)n0 * DH, DH, DH, acc);
  EPI_SETUP();
  #pragma unroll
  for (int mi = 0; mi < 2; ++mi)
    #pragma unroll
    for (int ni = 0; ni < 2; ++ni)
      #pragma unroll
      for (int r = 0; r < 4; ++r) {
        const int m = wm + mi * 16 + fg * 4 + r;
        const int n = n0 + wn + ni * 16 + fr;
        const float v = acc[mi][ni][r] + bo[n];
        pred[((size_t)m * FUT + f) * DOUT + n] = v;
        zn[(size_t)m * KTOT + n] = (__bf16)v;
      }
}

// ---------------------------------------------------------------------------
extern "C" void kernel_launch(void* const* d_in, const int* in_sizes, int n_in,
                              void* d_out, int out_size, void* d_ws, size_t ws_size,
                              hipStream_t stream)
{
  const float* x  = (const float*)d_in[0];
  const float* Wh = (const float*)d_in[1];
  const float* bh = (const float*)d_in[2];
  const float* Wo = (const float*)d_in[3];
  const float* bo = (const float*)d_in[4];

  char* ws = (char*)d_ws;
  __bf16* WhT = (__bf16*)ws;                               // [DH][KTOT]   12 MB
  __bf16* WoT = WhT + (size_t)DH * KTOT;                   // [DOUT][DH]    4 MB
  __bf16* HX  = WoT + (size_t)DOUT * DH;                   // [Sz][Bz][DH] 128 MB
  __bf16* zf  = HX + (size_t)Sz * Bz * DH;                 // [2][Bz][KTOT] .8 MB
  unsigned int* flags = (unsigned int*)(zf + (size_t)2 * Bz * KTOT); // 1 MB

  float* out  = (float*)d_out;
  float* pred = out + (size_t)Bz * Sz * DOUT;

  const dim3 blk(256);

  k_transp<<<dim3(KTOT / 64, DH / 64), blk, 0, stream>>>(Wh, WhT, KTOT, DH);
  k_transp<<<dim3(DH / 64, DOUT / 64), blk, 0, stream>>>(Wo, WoT, DH, DOUT);

  hipMemsetAsync(flags, 0, (size_t)Sz * 4 * 128 * sizeof(unsigned int), stream);

  k_xw128<<<dim3(DH / 128, (Bz * Sz) / 128), blk, 0, stream>>>(x, WhT, bh, HX);

  {
    const __bf16* a0 = WhT; __bf16* a1 = HX; unsigned int* a2 = flags;
    void* args[] = { (void*)&a0, (void*)&a1, (void*)&a2 };
    hipLaunchCooperativeKernel((const void*)k_rnn, dim3(128), dim3(512), args,
                               0, stream);
  }

  k_out128<<<dim3(DOUT / 128, (Bz * Sz) / 128), blk, 0, stream>>>(HX, WoT, bo, out);

  k_finit<<<dim3(Bz), blk, 0, stream>>>(x, HX, zf);
  for (int f = 0; f < FUT; ++f) {
    __bf16* zc = zf + (size_t)(f & 1) * Bz * KTOT;
    __bf16* zn = zf + (size_t)((f & 1) ^ 1) * Bz * KTOT;
    k_fstep<<<dim3(DH / 64), blk, 0, stream>>>(zc, zn, WhT, bh);
    k_fout<<<dim3(DOUT / 64), blk, 0, stream>>>(zn, WoT, bo, pred, f);
  }
}

// Round 15
// 2928.349 us; speedup vs baseline: 1.2852x; 1.1007x over previous
//
#include <hip/hip_runtime.h>
#include <hip/hip_bf16.h>
#include <math.h>

#define Bz   64
#define Sz   512
#define DIN  1024
#define DH   2048
#define DOUT 1024
#define FUT  16
#define KTOT (DIN + DH)   // 3072

typedef __attribute__((ext_vector_type(8))) __bf16 bf16x8;
typedef __attribute__((ext_vector_type(4))) float  f32x4;

union U16x8 { uint4 u; bf16x8 v; };

__device__ __forceinline__ uint4 pack_bf8(float4 a, float4 b) {
  bf16x8 t;
  t[0]=(__bf16)a.x; t[1]=(__bf16)a.y; t[2]=(__bf16)a.z; t[3]=(__bf16)a.w;
  t[4]=(__bf16)b.x; t[5]=(__bf16)b.y; t[6]=(__bf16)b.z; t[7]=(__bf16)b.w;
  U16x8 u; u.v = t; return u.u;
}

// branch-free tanh: 1 - 2/(e^{2x}+1). Saturates to ±1.
__device__ __forceinline__ float fast_tanh(float x) {
  const float e = __builtin_amdgcn_exp2f(2.8853900817779268f * x);
  return 1.0f - 2.0f * __builtin_amdgcn_rcpf(e + 1.0f);
}

// async global->LDS, 16B per lane (dest = wave-uniform base + lane*16)
__device__ __forceinline__ void gload16(const void* g, void* l) {
  __builtin_amdgcn_global_load_lds(
      (const __attribute__((address_space(1))) unsigned int*)g,
      (__attribute__((address_space(3))) unsigned int*)l, 16, 0, 0);
}

// ---------------------------------------------------------------------------
// 64x64-tile GEMM core. AF32/BF32: convert fp32 operand rows to bf16 on stage.
// ---------------------------------------------------------------------------
template<bool AF32, bool BF32>
__device__ __forceinline__ void gemm_core(
    const void* __restrict__ Abase, size_t astride,
    const void* __restrict__ Bbase, size_t bstride,
    int K, f32x4 acc[2][2])
{
  __shared__ uint4 Al[2][512];
  __shared__ uint4 Bl[2][512];

  const int tid  = threadIdx.x;
  const int lane = tid & 63;
  const int wave = tid >> 6;
  const int wm = (wave >> 1) << 5;
  const int wn = (wave & 1) << 5;
  const int fr = lane & 15;
  const int fg = lane >> 4;

  const int srow = tid >> 2;
  const int sck  = (tid & 3) << 1;

  const int NK = K >> 6;
  if (NK <= 0) return;

  uint4 ra0, ra1, rb0, rb1;

  auto loadt = [&](int kt) {
    const int kelt = (kt << 6) + (sck << 3);
    if constexpr (AF32) {
      const float* ap = (const float*)Abase + (size_t)srow * astride + kelt;
      float4 a0 = *(const float4*)(ap);
      float4 a1 = *(const float4*)(ap + 4);
      float4 a2 = *(const float4*)(ap + 8);
      float4 a3 = *(const float4*)(ap + 12);
      ra0 = pack_bf8(a0, a1);
      ra1 = pack_bf8(a2, a3);
    } else {
      const __bf16* ap = (const __bf16*)Abase + (size_t)srow * astride + kelt;
      ra0 = *(const uint4*)(ap);
      ra1 = *(const uint4*)(ap + 8);
    }
    if constexpr (BF32) {
      const float* bp = (const float*)Bbase + (size_t)srow * bstride + kelt;
      float4 b0 = *(const float4*)(bp);
      float4 b1 = *(const float4*)(bp + 4);
      float4 b2 = *(const float4*)(bp + 8);
      float4 b3 = *(const float4*)(bp + 12);
      rb0 = pack_bf8(b0, b1);
      rb1 = pack_bf8(b2, b3);
    } else {
      const __bf16* bp = (const __bf16*)Bbase + (size_t)srow * bstride + kelt;
      rb0 = *(const uint4*)(bp);
      rb1 = *(const uint4*)(bp + 8);
    }
  };

  auto storet = [&](int buf) {
    const int x7 = srow & 7;
    Al[buf][srow * 8 + ( sck      ^ x7)] = ra0;
    Al[buf][srow * 8 + ((sck + 1) ^ x7)] = ra1;
    Bl[buf][srow * 8 + ( sck      ^ x7)] = rb0;
    Bl[buf][srow * 8 + ((sck + 1) ^ x7)] = rb1;
  };

  loadt(0);
  storet(0);
  __syncthreads();

  for (int kt = 0; kt < NK; ++kt) {
    const int  cur  = kt & 1;
    const bool more = (kt + 1) < NK;
    if (more) loadt(kt + 1);

    #pragma unroll
    for (int kk = 0; kk < 2; ++kk) {
      bf16x8 af[2], bfrag[2];
      #pragma unroll
      for (int mi = 0; mi < 2; ++mi) {
        const int row = wm + mi * 16 + fr;
        const int ck  = (kk * 4 + fg) ^ (row & 7);
        U16x8 u; u.u = Al[cur][row * 8 + ck]; af[mi] = u.v;
      }
      #pragma unroll
      for (int ni = 0; ni < 2; ++ni) {
        const int row = wn + ni * 16 + fr;
        const int ck  = (kk * 4 + fg) ^ (row & 7);
        U16x8 u; u.u = Bl[cur][row * 8 + ck]; bfrag[ni] = u.v;
      }
      #pragma unroll
      for (int mi = 0; mi < 2; ++mi)
        #pragma unroll
        for (int ni = 0; ni < 2; ++ni)
          acc[mi][ni] = __builtin_amdgcn_mfma_f32_16x16x32_bf16(
              af[mi], bfrag[ni], acc[mi][ni], 0, 0, 0);
    }

    __syncthreads();
    if (more) storet((kt + 1) & 1);
    __syncthreads();
  }
}

#define EPI_SETUP() \
  const int tid = threadIdx.x, lane = tid & 63, wave = tid >> 6; \
  const int wm = (wave >> 1) << 5, wn = (wave & 1) << 5; \
  const int fr = lane & 15, fg = lane >> 4;

// ---------------------------------------------------------------------------
__global__ __launch_bounds__(256) void k_transp(const float* __restrict__ W,
                                                __bf16* __restrict__ WT,
                                                int K, int N)
{
  __shared__ float T[64][65];
  const int k0 = blockIdx.x << 6, n0 = blockIdx.y << 6;
  const int c = threadIdx.x & 63, r4 = threadIdx.x >> 6;
  #pragma unroll
  for (int rr = 0; rr < 16; ++rr) {
    const int r = rr * 4 + r4;
    T[r][c] = W[(size_t)(k0 + r) * N + n0 + c];
  }
  __syncthreads();
  #pragma unroll
  for (int rr = 0; rr < 16; ++rr) {
    const int r = rr * 4 + r4;
    WT[(size_t)(n0 + r) * K + k0 + c] = (__bf16)T[c][r];
  }
}

// ---------------------------------------------------------------------------
// Phase A (m97-style 128x128): HX[s][b][n] = bf16(x_row . Wx[:,n] + bh[n])
// ---------------------------------------------------------------------------
__global__ __launch_bounds__(256) void k_xw128(const float* __restrict__ x,
                                               const __bf16* __restrict__ WhT,
                                               const float* __restrict__ bh,
                                               __bf16* __restrict__ HX)
{
  __shared__ __align__(16) uint4 As[1024];   // [128 rows][8 chunks] bf16
  __shared__ __align__(16) uint4 Bs[1024];

  const int n0 = blockIdx.x << 7;
  const int m0 = blockIdx.y << 7;
  const int tid = threadIdx.x, lane = tid & 63, w = tid >> 6;
  const int wr = w >> 1, wc = w & 1;
  const int fr = lane & 15, fg = lane >> 4;

  const int sr  = tid >> 3;
  const int sq  = tid & 7;
  const int sq2 = sq ^ (sr & 7);

  f32x4 acc[4][4] = {};

  for (int kt = 0; kt < DIN / 64; ++kt) {
    const int ko = kt << 6;
    #pragma unroll
    for (int j = 0; j < 4; ++j) {
      const float* ap = x + (size_t)(m0 + sr + 32 * j) * DIN + ko + (sq2 << 3);
      float4 a0 = *(const float4*)ap;
      float4 a1 = *(const float4*)(ap + 4);
      As[((sr + 32 * j) << 3) + sq] = pack_bf8(a0, a1);
      gload16(WhT + (size_t)(n0 + sr + 32 * j) * KTOT + ko + (sq2 << 3),
              (char*)Bs + (tid << 4) + (j << 12));
    }
    __syncthreads();
    #pragma unroll
    for (int kk = 0; kk < 2; ++kk) {
      bf16x8 af[4], bf_[4];
      const int kq = (kk << 2) + fg;
      #pragma unroll
      for (int mi = 0; mi < 4; ++mi) {
        const int row = (wr << 6) + (mi << 4) + fr;
        U16x8 u; u.u = As[(row << 3) + (kq ^ (row & 7))]; af[mi] = u.v;
      }
      #pragma unroll
      for (int ni = 0; ni < 4; ++ni) {
        const int row = (wc << 6) + (ni << 4) + fr;
        U16x8 u; u.u = Bs[(row << 3) + (kq ^ (row & 7))]; bf_[ni] = u.v;
      }
      #pragma unroll
      for (int mi = 0; mi < 4; ++mi)
        #pragma unroll
        for (int ni = 0; ni < 4; ++ni)
          acc[mi][ni] = __builtin_amdgcn_mfma_f32_16x16x32_bf16(
              af[mi], bf_[ni], acc[mi][ni], 0, 0, 0);
    }
    __syncthreads();
  }

  #pragma unroll
  for (int ni = 0; ni < 4; ++ni) {
    const int n = n0 + (wc << 6) + (ni << 4) + fr;
    const float bn = bh[n];
    #pragma unroll
    for (int mi = 0; mi < 4; ++mi)
      #pragma unroll
      for (int rr = 0; rr < 4; ++rr) {
        const int gf = m0 + (wr << 6) + (mi << 4) + (fg << 2) + rr;
        const int b = gf >> 9, s = gf & 511;     // row = b*512+s
        HX[((size_t)s * Bz + b) * DH + n] = (__bf16)(acc[mi][ni][rr] + bn);
      }
  }
}

// ---------------------------------------------------------------------------
// Phase C (m97-style 128x128): out[b][s][n] = HX_row . Wo[:,n] + bo[n]
// ---------------------------------------------------------------------------
__global__ __launch_bounds__(256) void k_out128(const __bf16* __restrict__ HX,
                                                const __bf16* __restrict__ WoT,
                                                const float* __restrict__ bo,
                                                float* __restrict__ out)
{
  __shared__ __align__(16) uint4 As[1024];
  __shared__ __align__(16) uint4 Bs[1024];

  const int n0 = blockIdx.x << 7;
  const int m0 = blockIdx.y << 7;
  const int tid = threadIdx.x, lane = tid & 63, w = tid >> 6;
  const int wr = w >> 1, wc = w & 1;
  const int fr = lane & 15, fg = lane >> 4;

  const int sr  = tid >> 3;
  const int sq  = tid & 7;
  const int sq2 = sq ^ (sr & 7);

  f32x4 acc[4][4] = {};

  for (int kt = 0; kt < DH / 64; ++kt) {
    const int ko = kt << 6;
    #pragma unroll
    for (int j = 0; j < 4; ++j) {
      gload16(HX + (size_t)(m0 + sr + 32 * j) * DH + ko + (sq2 << 3),
              (char*)As + (tid << 4) + (j << 12));
      gload16(WoT + (size_t)(n0 + sr + 32 * j) * DH + ko + (sq2 << 3),
              (char*)Bs + (tid << 4) + (j << 12));
    }
    __syncthreads();
    #pragma unroll
    for (int kk = 0; kk < 2; ++kk) {
      bf16x8 af[4], bf_[4];
      const int kq = (kk << 2) + fg;
      #pragma unroll
      for (int mi = 0; mi < 4; ++mi) {
        const int row = (wr << 6) + (mi << 4) + fr;
        U16x8 u; u.u = As[(row << 3) + (kq ^ (row & 7))]; af[mi] = u.v;
      }
      #pragma unroll
      for (int ni = 0; ni < 4; ++ni) {
        const int row = (wc << 6) + (ni << 4) + fr;
        U16x8 u; u.u = Bs[(row << 3) + (kq ^ (row & 7))]; bf_[ni] = u.v;
      }
      #pragma unroll
      for (int mi = 0; mi < 4; ++mi)
        #pragma unroll
        for (int ni = 0; ni < 4; ++ni)
          acc[mi][ni] = __builtin_amdgcn_mfma_f32_16x16x32_bf16(
              af[mi], bf_[ni], acc[mi][ni], 0, 0, 0);
    }
    __syncthreads();
  }

  #pragma unroll
  for (int ni = 0; ni < 4; ++ni) {
    const int n = n0 + (wc << 6) + (ni << 4) + fr;
    const float bn = bo[n];
    #pragma unroll
    for (int mi = 0; mi < 4; ++mi)
      #pragma unroll
      for (int rr = 0; rr < 4; ++rr) {
        const int gf = m0 + (wr << 6) + (mi << 4) + (fg << 2) + rr;
        const int s = gf >> 6, b = gf & 63;      // row = s*64+b
        out[((size_t)b * Sz + s) * DOUT + n] = acc[mi][ni][rr] + bn;
      }
  }
}

// ---------------------------------------------------------------------------
// Persistent RNN recurrence — r8's PROVEN protocol (sc0sc1 LLC flags).
// UNCHANGED from r11/r14.
// ---------------------------------------------------------------------------
__global__ __launch_bounds__(512, 2) void k_rnn(const __bf16* __restrict__ WhT,
                                                __bf16* __restrict__ HX,
                                                unsigned int* __restrict__ flags)
{
  __shared__ __align__(16) float RED[8 * 1056];   // 8 planes x [16][66]

  const int mb    = blockIdx.x & 3;
  const int nb    = blockIdx.x >> 2;      // 0..31
  const int nbase = nb << 6;              // 64-col slice
  const int tid   = threadIdx.x;
  const int lane  = tid & 63;
  const int w     = tid >> 6;             // 0..7 (K-eighth owner)
  const int l15   = lane & 15;
  const int l4    = lane >> 4;
  const int wavek = w << 8;               // K range [wavek, wavek+256)

  // ---- Whh slice resident as B-fragments ----
  bf16x8 wf[8][4];
  {
    const __bf16* wb = WhT + (size_t)(nbase + l15) * KTOT + DIN + wavek + (l4 << 3);
    #pragma unroll
    for (int kk = 0; kk < 8; ++kk)
      #pragma unroll
      for (int nt = 0; nt < 4; ++nt)
        wf[kk][nt] = *(const bf16x8*)(wb + (size_t)nt * 16 * KTOT + kk * 32);
  }

  const int orow = tid >> 5;
  const int cp   = tid & 31;
  const int grow = (mb << 4) + orow;
  const int gcol = nbase + (cp << 1);

  for (int t = 0; t < Sz; ++t) {
    __bf16* Hc = HX + (size_t)t * Bz * DH;

    unsigned int xwp;
    asm volatile("global_load_dword %0, %1, off sc0 sc1"
                 : "=v"(xwp)
                 : "v"((const void*)(Hc + (size_t)grow * DH + gcol))
                 : "memory");

    f32x4 acc[4] = {};

    if (t > 0) {
      const unsigned int* fl = flags
          + (((size_t)(t - 1) * 4 + mb) << 7) + (((w << 2) + (lane & 3)) << 2);
      for (;;) {
        unsigned int f;
        asm volatile("global_load_dword %0, %1, off sc0 sc1\n\t"
                     "s_waitcnt vmcnt(0)"
                     : "=v"(f) : "v"((const void*)fl) : "memory");
        if (__all((int)(f == 1u))) break;
        __builtin_amdgcn_s_sleep(1);
      }

      const __bf16* Hp = HX + (size_t)(t - 1) * Bz * DH
                       + (size_t)((mb << 4) + l15) * DH + wavek + (l4 << 3);
      bf16x8 a[8];
      #pragma unroll
      for (int kk = 0; kk < 8; ++kk)
        a[kk] = *(const bf16x8*)(Hp + kk * 32);

      #pragma unroll
      for (int kk = 0; kk < 8; ++kk)
        #pragma unroll
        for (int nt = 0; nt < 4; ++nt)
          asm("v_mfma_f32_16x16x32_bf16 %0, %1, %2, %0"
              : "+v"(acc[nt]) : "v"(a[kk]), "a"(wf[kk][nt]));
    }

    #pragma unroll
    for (int nt = 0; nt < 4; ++nt)
      #pragma unroll
      for (int r = 0; r < 4; ++r)
        RED[w * 1056 + ((l4 << 2) + r) * 66 + (nt << 4) + l15] = acc[nt][r];
    __syncthreads();

    float sx = 0.f, sy = 0.f;
    #pragma unroll
    for (int p = 0; p < 8; ++p) {
      const float2 v = *(const float2*)&RED[p * 1056 + orow * 66 + (cp << 1)];
      sx += v.x; sy += v.y;
    }

    asm volatile("s_waitcnt vmcnt(0)" : "+v"(xwp) :: "memory");
    union { unsigned int u; __bf16 h[2]; } ux; ux.u = xwp;
    union { unsigned int u; __bf16 h[2]; } po;
    po.h[0] = (__bf16)fast_tanh(sx + (float)ux.h[0]);
    po.h[1] = (__bf16)fast_tanh(sy + (float)ux.h[1]);

    asm volatile("global_store_dword %0, %1, off sc0 sc1"
                 :: "v"((void*)(Hc + (size_t)grow * DH + gcol)), "v"(po.u)
                 : "memory");
    asm volatile("s_waitcnt vmcnt(0)" ::: "memory");
    __syncthreads();
    if (tid == 0) {
      unsigned int* fp = flags + (((size_t)t * 4 + mb) << 7) + (nb << 2);
      asm volatile("global_store_dword %0, %1, off sc0 sc1"
                   :: "v"((void*)fp), "v"(1u) : "memory");
    }
  }
}

// ---------------------------------------------------------------------------
// Wc prep: WcT[n][k] = bf16( sum_j Wh[j][n]*Wo[k][j] + Wh[DIN+k][n] )
//   A = WhT rows n (bf16, cols j<DIN), B = Wo rows k (fp32, conv on stage).
//   grid (k-tiles 32, n-tiles 32). Output coalesced in k.
// ---------------------------------------------------------------------------
__global__ __launch_bounds__(256) void k_wcomb(const __bf16* __restrict__ WhT,
                                               const float* __restrict__ Wo,
                                               __bf16* __restrict__ WcT)
{
  const int k0 = blockIdx.x << 6;
  const int n0 = blockIdx.y << 6;
  f32x4 acc[2][2] = {};
  gemm_core<false, true>(WhT + (size_t)n0 * KTOT, KTOT,
                         Wo + (size_t)k0 * DOUT, DOUT, DIN, acc);
  EPI_SETUP();
  #pragma unroll
  for (int mi = 0; mi < 2; ++mi)
    #pragma unroll
    for (int ni = 0; ni < 2; ++ni)
      #pragma unroll
      for (int r = 0; r < 4; ++r) {
        const int n = n0 + wm + mi * 16 + fg * 4 + r;
        const int k = k0 + wn + ni * 16 + fr;
        WcT[(size_t)n * DH + k] =
            (__bf16)(acc[mi][ni][r] + (float)WhT[(size_t)n * KTOT + DIN + k]);
      }
}

// ---------------------------------------------------------------------------
// bc[n] = bh[n] + sum_j bo[j]*Wh[j][n]    grid 512 x 256 (wave per n)
// ---------------------------------------------------------------------------
__global__ __launch_bounds__(256) void k_bc(const float* __restrict__ bh,
                                            const float* __restrict__ bo,
                                            const __bf16* __restrict__ WhT,
                                            float* __restrict__ bc)
{
  const int lane = threadIdx.x & 63;
  const int n = blockIdx.x * 4 + (threadIdx.x >> 6);
  float s = 0.f;
  for (int j0 = 0; j0 < DIN; j0 += 64)
    s += bo[j0 + lane] * (float)WhT[(size_t)n * KTOT + j0 + lane];
  #pragma unroll
  for (int off = 32; off; off >>= 1) s += __shfl_down(s, off);
  if (lane == 0) bc[n] = bh[n] + s;
}

// ---------------------------------------------------------------------------
// Future init: zs[0] = [ bf16(x[:,S-1,:]), H[S-1] ]   grid (Bz)
// ---------------------------------------------------------------------------
__global__ __launch_bounds__(256) void k_finit(const float* __restrict__ x,
                                               const __bf16* __restrict__ HX,
                                               __bf16* __restrict__ zs0)
{
  const int b = blockIdx.x;
  for (int k = threadIdx.x; k < DIN; k += 256)
    zs0[(size_t)b * KTOT + k] =
        (__bf16)x[((size_t)b * Sz + (Sz - 1)) * DIN + k];
  for (int k = threadIdx.x; k < DH; k += 256)
    zs0[(size_t)b * KTOT + DIN + k] =
        HX[(size_t)(Sz - 1) * Bz * DH + (size_t)b * DH + k];
}

// ---------------------------------------------------------------------------
// f=0 step (original form, K=3072): zs[1].h = tanh(zs[0] @ Wh + bh)
// ---------------------------------------------------------------------------
__global__ __launch_bounds__(256) void k_fstep(const __bf16* __restrict__ zc,
                                               __bf16* __restrict__ zn,
                                               const __bf16* __restrict__ WhT,
                                               const float* __restrict__ bh)
{
  const int n0 = blockIdx.x << 6;
  f32x4 acc[2][2] = {};
  gemm_core<false, false>(zc, KTOT, WhT + (size_t)n0 * KTOT, KTOT, KTOT, acc);
  EPI_SETUP();
  #pragma unroll
  for (int mi = 0; mi < 2; ++mi)
    #pragma unroll
    for (int ni = 0; ni < 2; ++ni)
      #pragma unroll
      for (int r = 0; r < 4; ++r) {
        const int m = wm + mi * 16 + fg * 4 + r;
        const int n = n0 + wn + ni * 16 + fr;
        zn[(size_t)m * KTOT + DIN + n] = (__bf16)fast_tanh(acc[mi][ni][r] + bh[n]);
      }
}

// ---------------------------------------------------------------------------
// Combined future step (f>=1): zs[f+1].h = tanh( zs[f].h @ Wc + bc ), K=2048
// ---------------------------------------------------------------------------
__global__ __launch_bounds__(256) void k_fstepc(const __bf16* __restrict__ gh,
                                                __bf16* __restrict__ zn,
                                                const __bf16* __restrict__ WcT,
                                                const float* __restrict__ bc)
{
  const int n0 = blockIdx.x << 6;
  f32x4 acc[2][2] = {};
  gemm_core<false, false>(gh, KTOT, WcT + (size_t)n0 * DH, DH, DH, acc);
  EPI_SETUP();
  #pragma unroll
  for (int mi = 0; mi < 2; ++mi)
    #pragma unroll
    for (int ni = 0; ni < 2; ++ni)
      #pragma unroll
      for (int r = 0; r < 4; ++r) {
        const int m = wm + mi * 16 + fg * 4 + r;
        const int n = n0 + wn + ni * 16 + fr;
        zn[(size_t)m * KTOT + DIN + n] = (__bf16)fast_tanh(acc[mi][ni][r] + bc[n]);
      }
}

// ---------------------------------------------------------------------------
// Batched pred: pred[b][f][n] = zs[f+1].h[b] . Wo[:,n] + bo[n]
//   A rows m=f*64+b at zs + (64+m)*KTOT + DIN (uniform stride KTOT), M=1024
//   grid (n-tiles 16, m-tiles 16)
// ---------------------------------------------------------------------------
__global__ __launch_bounds__(256) void k_predb(const __bf16* __restrict__ zs,
                                               const __bf16* __restrict__ WoT,
                                               const float* __restrict__ bo,
                                               float* __restrict__ pred)
{
  const int n0 = blockIdx.x << 6;
  const int m0 = blockIdx.y << 6;
  f32x4 acc[2][2] = {};
  gemm_core<false, false>(zs + (size_t)(64 + m0) * KTOT + DIN, KTOT,
                          WoT + (size_t)n0 * DH, DH, DH, acc);
  EPI_SETUP();
  #pragma unroll
  for (int mi = 0; mi < 2; ++mi)
    #pragma unroll
    for (int ni = 0; ni < 2; ++ni)
      #pragma unroll
      for (int r = 0; r < 4; ++r) {
        const int m = m0 + wm + mi * 16 + fg * 4 + r;
        const int n = n0 + wn + ni * 16 + fr;
        const int f = m >> 6, b = m & 63;
        pred[((size_t)b * FUT + f) * DOUT + n] = acc[mi][ni][r] + bo[n];
      }
}

// ---------------------------------------------------------------------------
extern "C" void kernel_launch(void* const* d_in, const int* in_sizes, int n_in,
                              void* d_out, int out_size, void* d_ws, size_t ws_size,
                              hipStream_t stream)
{
  const float* x  = (const float*)d_in[0];
  const float* Wh = (const float*)d_in[1];
  const float* bh = (const float*)d_in[2];
  const float* Wo = (const float*)d_in[3];
  const float* bo = (const float*)d_in[4];

  char* ws = (char*)d_ws;
  __bf16* WhT = (__bf16*)ws;                               // [DH][KTOT]   12 MB
  __bf16* WoT = WhT + (size_t)DH * KTOT;                   // [DOUT][DH]    4 MB
  __bf16* HX  = WoT + (size_t)DOUT * DH;                   // [Sz][Bz][DH] 128 MB
  unsigned int* flags = (unsigned int*)(HX + (size_t)Sz * Bz * DH); // 1 MB

  // Future-phase buffers OVERLAY HX (free after k_out128; k_finit reads only
  // HX[Sz-1] at byte offset ~127.75MB — no clash with the first ~16MB):
  char* hb = (char*)HX;
  __bf16* WcT = (__bf16*)hb;                        // [DH][DH] bf16, 8 MB
  float*  bc  = (float*)(hb + (8u << 20));          // [DH] f32, 8 KB
  __bf16* zs  = (__bf16*)(hb + (9u << 20));         // [17][Bz][KTOT], 6.7 MB

  float* out  = (float*)d_out;
  float* pred = out + (size_t)Bz * Sz * DOUT;

  const dim3 blk(256);

  k_transp<<<dim3(KTOT / 64, DH / 64), blk, 0, stream>>>(Wh, WhT, KTOT, DH);
  k_transp<<<dim3(DH / 64, DOUT / 64), blk, 0, stream>>>(Wo, WoT, DH, DOUT);

  hipMemsetAsync(flags, 0, (size_t)Sz * 4 * 128 * sizeof(unsigned int), stream);

  k_xw128<<<dim3(DH / 128, (Bz * Sz) / 128), blk, 0, stream>>>(x, WhT, bh, HX);

  {
    const __bf16* a0 = WhT; __bf16* a1 = HX; unsigned int* a2 = flags;
    void* args[] = { (void*)&a0, (void*)&a1, (void*)&a2 };
    hipLaunchCooperativeKernel((const void*)k_rnn, dim3(128), dim3(512), args,
                               0, stream);
  }

  k_out128<<<dim3(DOUT / 128, (Bz * Sz) / 128), blk, 0, stream>>>(HX, WoT, bo, out);

  // ---- future phase (algebraically collapsed) ----
  k_finit<<<dim3(Bz), blk, 0, stream>>>(x, HX, zs);   // reads HX[Sz-1] first
  k_wcomb<<<dim3(DH / 64, DH / 64), blk, 0, stream>>>(WhT, Wo, WcT);
  k_bc<<<dim3(DH / 4), blk, 0, stream>>>(bh, bo, WhT, bc);

  k_fstep<<<dim3(DH / 64), blk, 0, stream>>>(zs, zs + (size_t)Bz * KTOT, WhT, bh);
  for (int f = 1; f < FUT; ++f) {
    const __bf16* gh = zs + (size_t)f * Bz * KTOT + DIN;
    __bf16*       zn = zs + (size_t)(f + 1) * Bz * KTOT;
    k_fstepc<<<dim3(DH / 64), blk, 0, stream>>>(gh, zn, WcT, bc);
  }
  k_predb<<<dim3(DOUT / 64, (FUT * Bz) / 64), blk, 0, stream>>>(zs, WoT, bo, pred);
}

// Round 16
// 2909.578 us; speedup vs baseline: 1.2935x; 1.0065x over previous
//
#include <hip/hip_runtime.h>
#include <hip/hip_bf16.h>
#include <math.h>

#define Bz   64
#define Sz   512
#define DIN  1024
#define DH   2048
#define DOUT 1024
#define FUT  16
#define KTOT (DIN + DH)   // 3072

typedef __attribute__((ext_vector_type(8))) __bf16 bf16x8;
typedef __attribute__((ext_vector_type(4))) float  f32x4;

union U16x8 { uint4 u; bf16x8 v; };

__device__ __forceinline__ uint4 pack_bf8(float4 a, float4 b) {
  bf16x8 t;
  t[0]=(__bf16)a.x; t[1]=(__bf16)a.y; t[2]=(__bf16)a.z; t[3]=(__bf16)a.w;
  t[4]=(__bf16)b.x; t[5]=(__bf16)b.y; t[6]=(__bf16)b.z; t[7]=(__bf16)b.w;
  U16x8 u; u.v = t; return u.u;
}

// branch-free tanh: 1 - 2/(e^{2x}+1). Saturates to ±1.
__device__ __forceinline__ float fast_tanh(float x) {
  const float e = __builtin_amdgcn_exp2f(2.8853900817779268f * x);
  return 1.0f - 2.0f * __builtin_amdgcn_rcpf(e + 1.0f);
}

// async global->LDS, 16B per lane (dest = wave-uniform base + lane*16)
__device__ __forceinline__ void gload16(const void* g, void* l) {
  __builtin_amdgcn_global_load_lds(
      (const __attribute__((address_space(1))) unsigned int*)g,
      (__attribute__((address_space(3))) unsigned int*)l, 16, 0, 0);
}

// ---------------------------------------------------------------------------
// 64x64-tile GEMM core. AF32/BF32: convert fp32 operand rows to bf16 on stage.
// ---------------------------------------------------------------------------
template<bool AF32, bool BF32>
__device__ __forceinline__ void gemm_core(
    const void* __restrict__ Abase, size_t astride,
    const void* __restrict__ Bbase, size_t bstride,
    int K, f32x4 acc[2][2])
{
  __shared__ uint4 Al[2][512];
  __shared__ uint4 Bl[2][512];

  const int tid  = threadIdx.x;
  const int lane = tid & 63;
  const int wave = tid >> 6;
  const int wm = (wave >> 1) << 5;
  const int wn = (wave & 1) << 5;
  const int fr = lane & 15;
  const int fg = lane >> 4;

  const int srow = tid >> 2;
  const int sck  = (tid & 3) << 1;

  const int NK = K >> 6;
  if (NK <= 0) return;

  uint4 ra0, ra1, rb0, rb1;

  auto loadt = [&](int kt) {
    const int kelt = (kt << 6) + (sck << 3);
    if constexpr (AF32) {
      const float* ap = (const float*)Abase + (size_t)srow * astride + kelt;
      float4 a0 = *(const float4*)(ap);
      float4 a1 = *(const float4*)(ap + 4);
      float4 a2 = *(const float4*)(ap + 8);
      float4 a3 = *(const float4*)(ap + 12);
      ra0 = pack_bf8(a0, a1);
      ra1 = pack_bf8(a2, a3);
    } else {
      const __bf16* ap = (const __bf16*)Abase + (size_t)srow * astride + kelt;
      ra0 = *(const uint4*)(ap);
      ra1 = *(const uint4*)(ap + 8);
    }
    if constexpr (BF32) {
      const float* bp = (const float*)Bbase + (size_t)srow * bstride + kelt;
      float4 b0 = *(const float4*)(bp);
      float4 b1 = *(const float4*)(bp + 4);
      float4 b2 = *(const float4*)(bp + 8);
      float4 b3 = *(const float4*)(bp + 12);
      rb0 = pack_bf8(b0, b1);
      rb1 = pack_bf8(b2, b3);
    } else {
      const __bf16* bp = (const __bf16*)Bbase + (size_t)srow * bstride + kelt;
      rb0 = *(const uint4*)(bp);
      rb1 = *(const uint4*)(bp + 8);
    }
  };

  auto storet = [&](int buf) {
    const int x7 = srow & 7;
    Al[buf][srow * 8 + ( sck      ^ x7)] = ra0;
    Al[buf][srow * 8 + ((sck + 1) ^ x7)] = ra1;
    Bl[buf][srow * 8 + ( sck      ^ x7)] = rb0;
    Bl[buf][srow * 8 + ((sck + 1) ^ x7)] = rb1;
  };

  loadt(0);
  storet(0);
  __syncthreads();

  for (int kt = 0; kt < NK; ++kt) {
    const int  cur  = kt & 1;
    const bool more = (kt + 1) < NK;
    if (more) loadt(kt + 1);

    #pragma unroll
    for (int kk = 0; kk < 2; ++kk) {
      bf16x8 af[2], bfrag[2];
      #pragma unroll
      for (int mi = 0; mi < 2; ++mi) {
        const int row = wm + mi * 16 + fr;
        const int ck  = (kk * 4 + fg) ^ (row & 7);
        U16x8 u; u.u = Al[cur][row * 8 + ck]; af[mi] = u.v;
      }
      #pragma unroll
      for (int ni = 0; ni < 2; ++ni) {
        const int row = wn + ni * 16 + fr;
        const int ck  = (kk * 4 + fg) ^ (row & 7);
        U16x8 u; u.u = Bl[cur][row * 8 + ck]; bfrag[ni] = u.v;
      }
      #pragma unroll
      for (int mi = 0; mi < 2; ++mi)
        #pragma unroll
        for (int ni = 0; ni < 2; ++ni)
          acc[mi][ni] = __builtin_amdgcn_mfma_f32_16x16x32_bf16(
              af[mi], bfrag[ni], acc[mi][ni], 0, 0, 0);
    }

    __syncthreads();
    if (more) storet((kt + 1) & 1);
    __syncthreads();
  }
}

#define EPI_SETUP() \
  const int tid = threadIdx.x, lane = tid & 63, wave = tid >> 6; \
  const int wm = (wave >> 1) << 5, wn = (wave & 1) << 5; \
  const int fr = lane & 15, fg = lane >> 4;

// ---------------------------------------------------------------------------
__global__ __launch_bounds__(256) void k_transp(const float* __restrict__ W,
                                                __bf16* __restrict__ WT,
                                                int K, int N)
{
  __shared__ float T[64][65];
  const int k0 = blockIdx.x << 6, n0 = blockIdx.y << 6;
  const int c = threadIdx.x & 63, r4 = threadIdx.x >> 6;
  #pragma unroll
  for (int rr = 0; rr < 16; ++rr) {
    const int r = rr * 4 + r4;
    T[r][c] = W[(size_t)(k0 + r) * N + n0 + c];
  }
  __syncthreads();
  #pragma unroll
  for (int rr = 0; rr < 16; ++rr) {
    const int r = rr * 4 + r4;
    WT[(size_t)(n0 + r) * K + k0 + c] = (__bf16)T[c][r];
  }
}

// ---------------------------------------------------------------------------
// Phase A (m97-style 128x128): HX[s][b][n] = bf16(x_row . Wx[:,n] + bh[n])
// ---------------------------------------------------------------------------
__global__ __launch_bounds__(256) void k_xw128(const float* __restrict__ x,
                                               const __bf16* __restrict__ WhT,
                                               const float* __restrict__ bh,
                                               __bf16* __restrict__ HX)
{
  __shared__ __align__(16) uint4 As[1024];   // [128 rows][8 chunks] bf16
  __shared__ __align__(16) uint4 Bs[1024];

  const int n0 = blockIdx.x << 7;
  const int m0 = blockIdx.y << 7;
  const int tid = threadIdx.x, lane = tid & 63, w = tid >> 6;
  const int wr = w >> 1, wc = w & 1;
  const int fr = lane & 15, fg = lane >> 4;

  const int sr  = tid >> 3;
  const int sq  = tid & 7;
  const int sq2 = sq ^ (sr & 7);

  f32x4 acc[4][4] = {};

  for (int kt = 0; kt < DIN / 64; ++kt) {
    const int ko = kt << 6;
    #pragma unroll
    for (int j = 0; j < 4; ++j) {
      const float* ap = x + (size_t)(m0 + sr + 32 * j) * DIN + ko + (sq2 << 3);
      float4 a0 = *(const float4*)ap;
      float4 a1 = *(const float4*)(ap + 4);
      As[((sr + 32 * j) << 3) + sq] = pack_bf8(a0, a1);
      gload16(WhT + (size_t)(n0 + sr + 32 * j) * KTOT + ko + (sq2 << 3),
              (char*)Bs + (tid << 4) + (j << 12));
    }
    __syncthreads();
    #pragma unroll
    for (int kk = 0; kk < 2; ++kk) {
      bf16x8 af[4], bf_[4];
      const int kq = (kk << 2) + fg;
      #pragma unroll
      for (int mi = 0; mi < 4; ++mi) {
        const int row = (wr << 6) + (mi << 4) + fr;
        U16x8 u; u.u = As[(row << 3) + (kq ^ (row & 7))]; af[mi] = u.v;
      }
      #pragma unroll
      for (int ni = 0; ni < 4; ++ni) {
        const int row = (wc << 6) + (ni << 4) + fr;
        U16x8 u; u.u = Bs[(row << 3) + (kq ^ (row & 7))]; bf_[ni] = u.v;
      }
      #pragma unroll
      for (int mi = 0; mi < 4; ++mi)
        #pragma unroll
        for (int ni = 0; ni < 4; ++ni)
          acc[mi][ni] = __builtin_amdgcn_mfma_f32_16x16x32_bf16(
              af[mi], bf_[ni], acc[mi][ni], 0, 0, 0);
    }
    __syncthreads();
  }

  #pragma unroll
  for (int ni = 0; ni < 4; ++ni) {
    const int n = n0 + (wc << 6) + (ni << 4) + fr;
    const float bn = bh[n];
    #pragma unroll
    for (int mi = 0; mi < 4; ++mi)
      #pragma unroll
      for (int rr = 0; rr < 4; ++rr) {
        const int gf = m0 + (wr << 6) + (mi << 4) + (fg << 2) + rr;
        const int b = gf >> 9, s = gf & 511;     // row = b*512+s
        HX[((size_t)s * Bz + b) * DH + n] = (__bf16)(acc[mi][ni][rr] + bn);
      }
  }
}

// ---------------------------------------------------------------------------
// Phase C (m97-style 128x128): out[b][s][n] = HX_row . Wo[:,n] + bo[n]
// ---------------------------------------------------------------------------
__global__ __launch_bounds__(256) void k_out128(const __bf16* __restrict__ HX,
                                                const __bf16* __restrict__ WoT,
                                                const float* __restrict__ bo,
                                                float* __restrict__ out)
{
  __shared__ __align__(16) uint4 As[1024];
  __shared__ __align__(16) uint4 Bs[1024];

  const int n0 = blockIdx.x << 7;
  const int m0 = blockIdx.y << 7;
  const int tid = threadIdx.x, lane = tid & 63, w = tid >> 6;
  const int wr = w >> 1, wc = w & 1;
  const int fr = lane & 15, fg = lane >> 4;

  const int sr  = tid >> 3;
  const int sq  = tid & 7;
  const int sq2 = sq ^ (sr & 7);

  f32x4 acc[4][4] = {};

  for (int kt = 0; kt < DH / 64; ++kt) {
    const int ko = kt << 6;
    #pragma unroll
    for (int j = 0; j < 4; ++j) {
      gload16(HX + (size_t)(m0 + sr + 32 * j) * DH + ko + (sq2 << 3),
              (char*)As + (tid << 4) + (j << 12));
      gload16(WoT + (size_t)(n0 + sr + 32 * j) * DH + ko + (sq2 << 3),
              (char*)Bs + (tid << 4) + (j << 12));
    }
    __syncthreads();
    #pragma unroll
    for (int kk = 0; kk < 2; ++kk) {
      bf16x8 af[4], bf_[4];
      const int kq = (kk << 2) + fg;
      #pragma unroll
      for (int mi = 0; mi < 4; ++mi) {
        const int row = (wr << 6) + (mi << 4) + fr;
        U16x8 u; u.u = As[(row << 3) + (kq ^ (row & 7))]; af[mi] = u.v;
      }
      #pragma unroll
      for (int ni = 0; ni < 4; ++ni) {
        const int row = (wc << 6) + (ni << 4) + fr;
        U16x8 u; u.u = Bs[(row << 3) + (kq ^ (row & 7))]; bf_[ni] = u.v;
      }
      #pragma unroll
      for (int mi = 0; mi < 4; ++mi)
        #pragma unroll
        for (int ni = 0; ni < 4; ++ni)
          acc[mi][ni] = __builtin_amdgcn_mfma_f32_16x16x32_bf16(
              af[mi], bf_[ni], acc[mi][ni], 0, 0, 0);
    }
    __syncthreads();
  }

  #pragma unroll
  for (int ni = 0; ni < 4; ++ni) {
    const int n = n0 + (wc << 6) + (ni << 4) + fr;
    const float bn = bo[n];
    #pragma unroll
    for (int mi = 0; mi < 4; ++mi)
      #pragma unroll
      for (int rr = 0; rr < 4; ++rr) {
        const int gf = m0 + (wr << 6) + (mi << 4) + (fg << 2) + rr;
        const int s = gf >> 6, b = gf & 63;      // row = s*64+b
        out[((size_t)b * Sz + s) * DOUT + n] = acc[mi][ni][rr] + bn;
      }
  }
}

// ---------------------------------------------------------------------------
// Persistent RNN recurrence — r8's PROVEN sc0sc1 LLC protocol. r15 -> r16:
// consumer side only: BALLOT-DRIVEN PER-PRODUCER A-load issue. One poll round
// reads all 4 flags (as before); as each producer turns ready its 2 dwordx4
// chunks are issued immediately (wave-uniform branches), hiding early
// producers' load latency under the straggler wait. MFMA order, publish path,
// and liveness are unchanged.
// ---------------------------------------------------------------------------
__global__ __launch_bounds__(512, 2) void k_rnn(const __bf16* __restrict__ WhT,
                                                __bf16* __restrict__ HX,
                                                unsigned int* __restrict__ flags)
{
  __shared__ __align__(16) float RED[8 * 1056];   // 8 planes x [16][66]

  const int mb    = blockIdx.x & 3;
  const int nb    = blockIdx.x >> 2;      // 0..31
  const int nbase = nb << 6;              // 64-col slice
  const int tid   = threadIdx.x;
  const int lane  = tid & 63;
  const int w     = tid >> 6;             // 0..7 (K-eighth owner)
  const int l15   = lane & 15;
  const int l4    = lane >> 4;
  const int wavek = w << 8;               // K range [wavek, wavek+256)

  // ---- Whh slice resident as B-fragments ----
  bf16x8 wf[8][4];
  {
    const __bf16* wb = WhT + (size_t)(nbase + l15) * KTOT + DIN + wavek + (l4 << 3);
    #pragma unroll
    for (int kk = 0; kk < 8; ++kk)
      #pragma unroll
      for (int nt = 0; nt < 4; ++nt)
        wf[kk][nt] = *(const bf16x8*)(wb + (size_t)nt * 16 * KTOT + kk * 32);
  }

  const int orow = tid >> 5;
  const int cp   = tid & 31;
  const int grow = (mb << 4) + orow;
  const int gcol = nbase + (cp << 1);

  for (int t = 0; t < Sz; ++t) {
    __bf16* Hc = HX + (size_t)t * Bz * DH;

    unsigned int xwp;
    asm volatile("global_load_dword %0, %1, off sc0 sc1"
                 : "=v"(xwp)
                 : "v"((const void*)(Hc + (size_t)grow * DH + gcol))
                 : "memory");

    f32x4 acc[4] = {};

    if (t > 0) {
      const unsigned int* fl = flags
          + (((size_t)(t - 1) * 4 + mb) << 7) + (((w << 2) + (lane & 3)) << 2);
      const __bf16* Hp = HX + (size_t)(t - 1) * Bz * DH
                       + (size_t)((mb << 4) + l15) * DH + wavek + (l4 << 3);

      uint4 a4[8];
      unsigned int pend = 0xFu;   // producers p=0..3 (p covers kk=2p,2p+1)
      do {
        unsigned int f;
        asm volatile("global_load_dword %0, %1, off sc0 sc1\n\t"
                     "s_waitcnt vmcnt(0)"
                     : "=v"(f) : "v"((const void*)fl) : "memory");
        const unsigned long long bal = __ballot((int)(f == 1u));
        const unsigned int rdy = ((unsigned int)bal & 0xFu) & pend;
        if (rdy & 1u) {   // producer 0 -> chunks kk=0,1 (cached loads)
          asm volatile("global_load_dwordx4 %0, %2, off\n\t"
                       "global_load_dwordx4 %1, %3, off"
                       : "=v"(a4[0]), "=v"(a4[1])
                       : "v"((const void*)(Hp)), "v"((const void*)(Hp + 32))
                       : "memory");
        }
        if (rdy & 2u) {   // producer 1 -> kk=2,3
          asm volatile("global_load_dwordx4 %0, %2, off\n\t"
                       "global_load_dwordx4 %1, %3, off"
                       : "=v"(a4[2]), "=v"(a4[3])
                       : "v"((const void*)(Hp + 64)), "v"((const void*)(Hp + 96))
                       : "memory");
        }
        if (rdy & 4u) {   // producer 2 -> kk=4,5
          asm volatile("global_load_dwordx4 %0, %2, off\n\t"
                       "global_load_dwordx4 %1, %3, off"
                       : "=v"(a4[4]), "=v"(a4[5])
                       : "v"((const void*)(Hp + 128)), "v"((const void*)(Hp + 160))
                       : "memory");
        }
        if (rdy & 8u) {   // producer 3 -> kk=6,7
          asm volatile("global_load_dwordx4 %0, %2, off\n\t"
                       "global_load_dwordx4 %1, %3, off"
                       : "=v"(a4[6]), "=v"(a4[7])
                       : "v"((const void*)(Hp + 192)), "v"((const void*)(Hp + 224))
                       : "memory");
        }
        pend &= ~rdy;
        if (pend) __builtin_amdgcn_s_sleep(1);
      } while (pend);

      asm volatile("s_waitcnt vmcnt(0)" ::: "memory");
      __builtin_amdgcn_sched_barrier(0);

      #pragma unroll
      for (int kk = 0; kk < 8; ++kk) {
        U16x8 ua; ua.u = a4[kk];
        #pragma unroll
        for (int nt = 0; nt < 4; ++nt)
          asm("v_mfma_f32_16x16x32_bf16 %0, %1, %2, %0"
              : "+v"(acc[nt]) : "v"(ua.v), "a"(wf[kk][nt]));
      }
    }

    #pragma unroll
    for (int nt = 0; nt < 4; ++nt)
      #pragma unroll
      for (int r = 0; r < 4; ++r)
        RED[w * 1056 + ((l4 << 2) + r) * 66 + (nt << 4) + l15] = acc[nt][r];
    __syncthreads();

    float sx = 0.f, sy = 0.f;
    #pragma unroll
    for (int p = 0; p < 8; ++p) {
      const float2 v = *(const float2*)&RED[p * 1056 + orow * 66 + (cp << 1)];
      sx += v.x; sy += v.y;
    }

    asm volatile("s_waitcnt vmcnt(0)" : "+v"(xwp) :: "memory");
    union { unsigned int u; __bf16 h[2]; } ux; ux.u = xwp;
    union { unsigned int u; __bf16 h[2]; } po;
    po.h[0] = (__bf16)fast_tanh(sx + (float)ux.h[0]);
    po.h[1] = (__bf16)fast_tanh(sy + (float)ux.h[1]);

    asm volatile("global_store_dword %0, %1, off sc0 sc1"
                 :: "v"((void*)(Hc + (size_t)grow * DH + gcol)), "v"(po.u)
                 : "memory");
    asm volatile("s_waitcnt vmcnt(0)" ::: "memory");
    __syncthreads();
    if (tid == 0) {
      unsigned int* fp = flags + (((size_t)t * 4 + mb) << 7) + (nb << 2);
      asm volatile("global_store_dword %0, %1, off sc0 sc1"
                   :: "v"((void*)fp), "v"(1u) : "memory");
    }
  }
}

// ---------------------------------------------------------------------------
// Wc prep: WcT[n][k] = bf16( sum_j Wh[j][n]*Wo[k][j] + Wh[DIN+k][n] )
// ---------------------------------------------------------------------------
__global__ __launch_bounds__(256) void k_wcomb(const __bf16* __restrict__ WhT,
                                               const float* __restrict__ Wo,
                                               __bf16* __restrict__ WcT)
{
  const int k0 = blockIdx.x << 6;
  const int n0 = blockIdx.y << 6;
  f32x4 acc[2][2] = {};
  gemm_core<false, true>(WhT + (size_t)n0 * KTOT, KTOT,
                         Wo + (size_t)k0 * DOUT, DOUT, DIN, acc);
  EPI_SETUP();
  #pragma unroll
  for (int mi = 0; mi < 2; ++mi)
    #pragma unroll
    for (int ni = 0; ni < 2; ++ni)
      #pragma unroll
      for (int r = 0; r < 4; ++r) {
        const int n = n0 + wm + mi * 16 + fg * 4 + r;
        const int k = k0 + wn + ni * 16 + fr;
        WcT[(size_t)n * DH + k] =
            (__bf16)(acc[mi][ni][r] + (float)WhT[(size_t)n * KTOT + DIN + k]);
      }
}

// ---------------------------------------------------------------------------
// bc[n] = bh[n] + sum_j bo[j]*Wh[j][n]    grid 512 x 256 (wave per n)
// ---------------------------------------------------------------------------
__global__ __launch_bounds__(256) void k_bc(const float* __restrict__ bh,
                                            const float* __restrict__ bo,
                                            const __bf16* __restrict__ WhT,
                                            float* __restrict__ bc)
{
  const int lane = threadIdx.x & 63;
  const int n = blockIdx.x * 4 + (threadIdx.x >> 6);
  float s = 0.f;
  for (int j0 = 0; j0 < DIN; j0 += 64)
    s += bo[j0 + lane] * (float)WhT[(size_t)n * KTOT + j0 + lane];
  #pragma unroll
  for (int off = 32; off; off >>= 1) s += __shfl_down(s, off);
  if (lane == 0) bc[n] = bh[n] + s;
}

// ---------------------------------------------------------------------------
// Future init: zs[0] = [ bf16(x[:,S-1,:]), H[S-1] ]   grid (Bz)
// ---------------------------------------------------------------------------
__global__ __launch_bounds__(256) void k_finit(const float* __restrict__ x,
                                               const __bf16* __restrict__ HX,
                                               __bf16* __restrict__ zs0)
{
  const int b = blockIdx.x;
  for (int k = threadIdx.x; k < DIN; k += 256)
    zs0[(size_t)b * KTOT + k] =
        (__bf16)x[((size_t)b * Sz + (Sz - 1)) * DIN + k];
  for (int k = threadIdx.x; k < DH; k += 256)
    zs0[(size_t)b * KTOT + DIN + k] =
        HX[(size_t)(Sz - 1) * Bz * DH + (size_t)b * DH + k];
}

// ---------------------------------------------------------------------------
// f=0 step (original form, K=3072): zs[1].h = tanh(zs[0] @ Wh + bh)
// ---------------------------------------------------------------------------
__global__ __launch_bounds__(256) void k_fstep(const __bf16* __restrict__ zc,
                                               __bf16* __restrict__ zn,
                                               const __bf16* __restrict__ WhT,
                                               const float* __restrict__ bh)
{
  const int n0 = blockIdx.x << 6;
  f32x4 acc[2][2] = {};
  gemm_core<false, false>(zc, KTOT, WhT + (size_t)n0 * KTOT, KTOT, KTOT, acc);
  EPI_SETUP();
  #pragma unroll
  for (int mi = 0; mi < 2; ++mi)
    #pragma unroll
    for (int ni = 0; ni < 2; ++ni)
      #pragma unroll
      for (int r = 0; r < 4; ++r) {
        const int m = wm + mi * 16 + fg * 4 + r;
        const int n = n0 + wn + ni * 16 + fr;
        zn[(size_t)m * KTOT + DIN + n] = (__bf16)fast_tanh(acc[mi][ni][r] + bh[n]);
      }
}

// ---------------------------------------------------------------------------
// Combined future step (f>=1): zs[f+1].h = tanh( zs[f].h @ Wc + bc ), K=2048
// ---------------------------------------------------------------------------
__global__ __launch_bounds__(256) void k_fstepc(const __bf16* __restrict__ gh,
                                                __bf16* __restrict__ zn,
                                                const __bf16* __restrict__ WcT,
                                                const float* __restrict__ bc)
{
  const int n0 = blockIdx.x << 6;
  f32x4 acc[2][2] = {};
  gemm_core<false, false>(gh, KTOT, WcT + (size_t)n0 * DH, DH, DH, acc);
  EPI_SETUP();
  #pragma unroll
  for (int mi = 0; mi < 2; ++mi)
    #pragma unroll
    for (int ni = 0; ni < 2; ++ni)
      #pragma unroll
      for (int r = 0; r < 4; ++r) {
        const int m = wm + mi * 16 + fg * 4 + r;
        const int n = n0 + wn + ni * 16 + fr;
        zn[(size_t)m * KTOT + DIN + n] = (__bf16)fast_tanh(acc[mi][ni][r] + bc[n]);
      }
}

// ---------------------------------------------------------------------------
// Batched pred: pred[b][f][n] = zs[f+1].h[b] . Wo[:,n] + bo[n]
// ---------------------------------------------------------------------------
__global__ __launch_bounds__(256) void k_predb(const __bf16* __restrict__ zs,
                                               const __bf16* __restrict__ WoT,
                                               const float* __restrict__ bo,
                                               float* __restrict__ pred)
{
  const int n0 = blockIdx.x << 6;
  const int m0 = blockIdx.y << 6;
  f32x4 acc[2][2] = {};
  gemm_core<false, false>(zs + (size_t)(64 + m0) * KTOT + DIN, KTOT,
                          WoT + (size_t)n0 * DH, DH, DH, acc);
  EPI_SETUP();
  #pragma unroll
  for (int mi = 0; mi < 2; ++mi)
    #pragma unroll
    for (int ni = 0; ni < 2; ++ni)
      #pragma unroll
      for (int r = 0; r < 4; ++r) {
        const int m = m0 + wm + mi * 16 + fg * 4 + r;
        const int n = n0 + wn + ni * 16 + fr;
        const int f = m >> 6, b = m & 63;
        pred[((size_t)b * FUT + f) * DOUT + n] = acc[mi][ni][r] + bo[n];
      }
}

// ---------------------------------------------------------------------------
extern "C" void kernel_launch(void* const* d_in, const int* in_sizes, int n_in,
                              void* d_out, int out_size, void* d_ws, size_t ws_size,
                              hipStream_t stream)
{
  const float* x  = (const float*)d_in[0];
  const float* Wh = (const float*)d_in[1];
  const float* bh = (const float*)d_in[2];
  const float* Wo = (const float*)d_in[3];
  const float* bo = (const float*)d_in[4];

  char* ws = (char*)d_ws;
  __bf16* WhT = (__bf16*)ws;                               // [DH][KTOT]   12 MB
  __bf16* WoT = WhT + (size_t)DH * KTOT;                   // [DOUT][DH]    4 MB
  __bf16* HX  = WoT + (size_t)DOUT * DH;                   // [Sz][Bz][DH] 128 MB
  unsigned int* flags = (unsigned int*)(HX + (size_t)Sz * Bz * DH); // 1 MB

  char* hb = (char*)HX;
  __bf16* WcT = (__bf16*)hb;                        // [DH][DH] bf16, 8 MB
  float*  bc  = (float*)(hb + (8u << 20));          // [DH] f32, 8 KB
  __bf16* zs  = (__bf16*)(hb + (9u << 20));         // [17][Bz][KTOT], 6.7 MB

  float* out  = (float*)d_out;
  float* pred = out + (size_t)Bz * Sz * DOUT;

  const dim3 blk(256);

  k_transp<<<dim3(KTOT / 64, DH / 64), blk, 0, stream>>>(Wh, WhT, KTOT, DH);
  k_transp<<<dim3(DH / 64, DOUT / 64), blk, 0, stream>>>(Wo, WoT, DH, DOUT);

  hipMemsetAsync(flags, 0, (size_t)Sz * 4 * 128 * sizeof(unsigned int), stream);

  k_xw128<<<dim3(DH / 128, (Bz * Sz) / 128), blk, 0, stream>>>(x, WhT, bh, HX);

  {
    const __bf16* a0 = WhT; __bf16* a1 = HX; unsigned int* a2 = flags;
    void* args[] = { (void*)&a0, (void*)&a1, (void*)&a2 };
    hipLaunchCooperativeKernel((const void*)k_rnn, dim3(128), dim3(512), args,
                               0, stream);
  }

  k_out128<<<dim3(DOUT / 128, (Bz * Sz) / 128), blk, 0, stream>>>(HX, WoT, bo, out);

  // ---- future phase (algebraically collapsed, r15) ----
  k_finit<<<dim3(Bz), blk, 0, stream>>>(x, HX, zs);
  k_wcomb<<<dim3(DH / 64, DH / 64), blk, 0, stream>>>(WhT, Wo, WcT);
  k_bc<<<dim3(DH / 4), blk, 0, stream>>>(bh, bo, WhT, bc);

  k_fstep<<<dim3(DH / 64), blk, 0, stream>>>(zs, zs + (size_t)Bz * KTOT, WhT, bh);
  for (int f = 1; f < FUT; ++f) {
    const __bf16* gh = zs + (size_t)f * Bz * KTOT + DIN;
    __bf16*       zn = zs + (size_t)(f + 1) * Bz * KTOT;
    k_fstepc<<<dim3(DH / 64), blk, 0, stream>>>(gh, zn, WcT, bc);
  }
  k_predb<<<dim3(DOUT / 64, (FUT * Bz) / 64), blk, 0, stream>>>(zs, WoT, bo, pred);
}